// Round 9
// baseline (509.372 us; speedup 1.0000x reference)
//
#include <hip/hip_runtime.h>
#include <math.h>

#define BB 8
#define TT 512
#define DD 256
#define DIM 512
#define KW 4
#define MM 2
#define HH 4
#define HDIM 64
#define LL 2
#define VV 272

typedef __attribute__((ext_vector_type(8))) short bf16x8;
typedef __attribute__((ext_vector_type(4))) float f32x4;

__device__ __forceinline__ float sigf(float x){ return 1.f/(1.f+__expf(-x)); }
__device__ __forceinline__ float siluf(float x){ return x/(1.f+__expf(-x)); }

__device__ __forceinline__ unsigned short f2bf(float f){
  unsigned int u = __float_as_uint(f);
  unsigned int r = (u + 0x7FFFu + ((u >> 16) & 1u)) >> 16;
  return (unsigned short)r;
}

// d-reduce via DPP only (no DS ops): xor1/xor2 = quad_perm, xor8 = row_ror:8
__device__ __forceinline__ float xor1_add(float x){
  int y = __builtin_amdgcn_update_dpp(0, __float_as_int(x), 0xB1, 0xF, 0xF, true);
  return x + __int_as_float(y);
}
__device__ __forceinline__ float xor2_add(float x){
  int y = __builtin_amdgcn_update_dpp(0, __float_as_int(x), 0x4E, 0xF, 0xF, true);
  return x + __int_as_float(y);
}
__device__ __forceinline__ float xor8_add(float x){
  int y = __builtin_amdgcn_update_dpp(0, __float_as_int(x), 0x128, 0xF, 0xF, true);
  return x + __int_as_float(y);
}

// async global->LDS, 16B per lane. LDS dest is wave-uniform base + lane*16.
__device__ __forceinline__ void gl_lds16(const float* g, float* l){
  __builtin_amdgcn_global_load_lds(
      (const __attribute__((address_space(1))) unsigned int*)g,
      (__attribute__((address_space(3))) unsigned int*)l,
      16, 0, 0);
}

// ---------------- embedding gather ----------------
__global__ void k_embed(const int* __restrict__ ids, const float* __restrict__ emb,
                        float* __restrict__ x){
  int row = blockIdx.x;
  int d = threadIdx.x;
  x[row*DD + d] = emb[ids[row]*DD + d];
}

// ---------------- rmsnorm (row of 256), 1 wave/row ----------------
__global__ void k_rmsnorm(const float* __restrict__ in, const float* __restrict__ w,
                          float* __restrict__ out){
  int row = blockIdx.x;
  int l = threadIdx.x;             // 64
  float4 v = *(const float4*)&in[row*DD + l*4];
  float ss = v.x*v.x + v.y*v.y + v.z*v.z + v.w*v.w;
  #pragma unroll
  for (int o = 32; o > 0; o >>= 1) ss += __shfl_xor(ss, o, 64);
  float sc = rsqrtf(ss*(1.f/DD) + 1e-6f);
  float4 wv = *(const float4*)&w[l*4];
  float4 r;
  r.x = v.x*sc*wv.x; r.y = v.y*sc*wv.y; r.z = v.z*sc*wv.z; r.w = v.w*sc*wv.w;
  *(float4*)&out[row*DD + l*4] = r;
}

// ---------------- bf16 MFMA GEMM: C[4096,N] = A[4096,K] @ B ----------------
template<bool BT>
__global__ void __launch_bounds__(256) k_gemm_bf(const float* __restrict__ A,
                                                 const float* __restrict__ B,
                                                 float* __restrict__ C, int N, int K){
  __shared__ unsigned short as[64][88];
  __shared__ unsigned short bs[64][88];
  const int tid = threadIdx.x;
  const int w = tid >> 6, l = tid & 63;
  const int m0 = blockIdx.y*64, n0 = blockIdx.x*64;
  f32x4 acc[4] = {};
  for (int k0 = 0; k0 < K; k0 += 64){
    { int ar = tid >> 2, ac = (tid & 3)*16;
      #pragma unroll
      for (int j = 0; j < 4; ++j){
        float4 a = *(const float4*)&A[(size_t)(m0+ar)*K + k0 + ac + j*4];
        ushort4 u = make_ushort4(f2bf(a.x), f2bf(a.y), f2bf(a.z), f2bf(a.w));
        *(ushort4*)&as[ar][ac + j*4] = u;
      }
    }
    if (!BT){
      int kr = tid >> 2, nc = (tid & 3)*16;
      #pragma unroll
      for (int j = 0; j < 4; ++j){
        int n = n0 + nc + j*4;
        float4 bv = make_float4(0.f,0.f,0.f,0.f);
        if (n < N) bv = *(const float4*)&B[(size_t)(k0+kr)*N + n];
        bs[nc+j*4+0][kr] = f2bf(bv.x);
        bs[nc+j*4+1][kr] = f2bf(bv.y);
        bs[nc+j*4+2][kr] = f2bf(bv.z);
        bs[nc+j*4+3][kr] = f2bf(bv.w);
      }
    } else {
      int nr = tid >> 2, kc = (tid & 3)*16;
      int n = n0 + nr;
      #pragma unroll
      for (int j = 0; j < 4; ++j){
        float4 bv = make_float4(0.f,0.f,0.f,0.f);
        if (n < N) bv = *(const float4*)&B[(size_t)n*K + k0 + kc + j*4];
        ushort4 u = make_ushort4(f2bf(bv.x), f2bf(bv.y), f2bf(bv.z), f2bf(bv.w));
        *(ushort4*)&bs[nr][kc + j*4] = u;
      }
    }
    __syncthreads();
    const int mr = w*16 + (l & 15);
    const int kb = (l >> 4)*8;
    #pragma unroll
    for (int kc2 = 0; kc2 < 2; ++kc2){
      bf16x8 af = *(const bf16x8*)&as[mr][kc2*32 + kb];
      #pragma unroll
      for (int nt = 0; nt < 4; ++nt){
        bf16x8 bfr = *(const bf16x8*)&bs[nt*16 + (l & 15)][kc2*32 + kb];
        acc[nt] = __builtin_amdgcn_mfma_f32_16x16x32_bf16(af, bfr, acc[nt], 0, 0, 0);
      }
    }
    __syncthreads();
  }
  #pragma unroll
  for (int nt = 0; nt < 4; ++nt){
    int col = n0 + nt*16 + (l & 15);
    if (col < N){
      #pragma unroll
      for (int r = 0; r < 4; ++r){
        int row = m0 + w*16 + (l >> 4)*4 + r;
        C[(size_t)row*N + col] = acc[nt][r];
      }
    }
  }
}

// ---- Wout GEMM with fused comb (A = p0+p1) and resid (x += y + A@Wout) ----
__global__ void __launch_bounds__(256) k_gemm_wout(const float* __restrict__ p0,
                                                   const float* __restrict__ p1,
                                                   const float* __restrict__ B,
                                                   const float* __restrict__ y,
                                                   float* __restrict__ x){
  __shared__ unsigned short as[64][88];
  __shared__ unsigned short bs[64][88];
  const int tid = threadIdx.x;
  const int w = tid >> 6, l = tid & 63;
  const int m0 = blockIdx.y*64, n0 = blockIdx.x*64;
  f32x4 acc[4] = {};
  for (int k0 = 0; k0 < DD; k0 += 64){
    { int ar = tid >> 2, ac = (tid & 3)*16;
      #pragma unroll
      for (int j = 0; j < 4; ++j){
        size_t off = (size_t)(m0+ar)*DD + k0 + ac + j*4;
        float4 a = *(const float4*)&p0[off];
        float4 b = *(const float4*)&p1[off];
        a.x += b.x; a.y += b.y; a.z += b.z; a.w += b.w;
        ushort4 u = make_ushort4(f2bf(a.x), f2bf(a.y), f2bf(a.z), f2bf(a.w));
        *(ushort4*)&as[ar][ac + j*4] = u;
      }
    }
    { int kr = tid >> 2, nc = (tid & 3)*16;
      #pragma unroll
      for (int j = 0; j < 4; ++j){
        float4 bv = *(const float4*)&B[(size_t)(k0+kr)*DD + n0 + nc + j*4];
        bs[nc+j*4+0][kr] = f2bf(bv.x);
        bs[nc+j*4+1][kr] = f2bf(bv.y);
        bs[nc+j*4+2][kr] = f2bf(bv.z);
        bs[nc+j*4+3][kr] = f2bf(bv.w);
      }
    }
    __syncthreads();
    const int mr = w*16 + (l & 15);
    const int kb = (l >> 4)*8;
    #pragma unroll
    for (int kc2 = 0; kc2 < 2; ++kc2){
      bf16x8 af = *(const bf16x8*)&as[mr][kc2*32 + kb];
      #pragma unroll
      for (int nt = 0; nt < 4; ++nt){
        bf16x8 bfr = *(const bf16x8*)&bs[nt*16 + (l & 15)][kc2*32 + kb];
        acc[nt] = __builtin_amdgcn_mfma_f32_16x16x32_bf16(af, bfr, acc[nt], 0, 0, 0);
      }
    }
    __syncthreads();
  }
  #pragma unroll
  for (int nt = 0; nt < 4; ++nt){
    int col = n0 + nt*16 + (l & 15);
    #pragma unroll
    for (int r = 0; r < 4; ++r){
      int row = m0 + w*16 + (l >> 4)*4 + r;
      size_t off = (size_t)row*DD + col;
      x[off] = x[off] + y[off] + acc[nt][r];
    }
  }
}

// ---------------- f32 GEMM (small-N path, proj only) ----------------
template<bool BT>
__global__ void __launch_bounds__(128) k_gemm(const float* __restrict__ A,
                                              const float* __restrict__ B,
                                              float* __restrict__ C, int N, int K){
  __shared__ float as[16][68];
  __shared__ float bs[16][68];
  const int tid = threadIdx.x;
  const int tx = tid & 15, ty = tid >> 4;
  const int m0 = blockIdx.y * 64, n0 = blockIdx.x * 64;
  float acc[8][4] = {};
  for (int k0 = 0; k0 < K; k0 += 16){
    #pragma unroll
    for (int r = 0; r < 2; ++r){
      int idx = tid + r*128;
      int mm = idx >> 2, kk4 = (idx & 3) * 4;
      float4 a = *(const float4*)&A[(size_t)(m0+mm)*K + k0 + kk4];
      as[kk4+0][mm] = a.x; as[kk4+1][mm] = a.y; as[kk4+2][mm] = a.z; as[kk4+3][mm] = a.w;
    }
    if (!BT){
      #pragma unroll
      for (int r = 0; r < 2; ++r){
        int idx = tid + r*128;
        int kk = idx >> 4, nn4 = (idx & 15) * 4;
        int n = n0 + nn4;
        float4 b = make_float4(0.f,0.f,0.f,0.f);
        if (n < N) b = *(const float4*)&B[(size_t)(k0+kk)*N + n];
        *(float4*)&bs[kk][nn4] = b;
      }
    } else {
      int nn = tid >> 1, kk8 = (tid & 1) * 8;
      int n = n0 + nn;
      float4 b0 = make_float4(0.f,0.f,0.f,0.f), b1 = b0;
      if (n < N){
        b0 = *(const float4*)&B[(size_t)n*K + k0 + kk8];
        b1 = *(const float4*)&B[(size_t)n*K + k0 + kk8 + 4];
      }
      bs[kk8+0][nn]=b0.x; bs[kk8+1][nn]=b0.y; bs[kk8+2][nn]=b0.z; bs[kk8+3][nn]=b0.w;
      bs[kk8+4][nn]=b1.x; bs[kk8+5][nn]=b1.y; bs[kk8+6][nn]=b1.z; bs[kk8+7][nn]=b1.w;
    }
    __syncthreads();
    #pragma unroll
    for (int kk = 0; kk < 16; ++kk){
      float ar[8], br[4];
      *(float4*)&ar[0] = *(const float4*)&as[kk][ty*4];
      *(float4*)&ar[4] = *(const float4*)&as[kk][32+ty*4];
      *(float4*)&br[0] = *(const float4*)&bs[kk][tx*4];
      #pragma unroll
      for (int i = 0; i < 8; ++i)
        #pragma unroll
        for (int j = 0; j < 4; ++j) acc[i][j] = fmaf(ar[i], br[j], acc[i][j]);
    }
    __syncthreads();
  }
  int n = n0 + tx*4;
  if (n < N){
    #pragma unroll
    for (int i = 0; i < 8; ++i){
      int row = m0 + ((i < 4) ? (ty*4 + i) : (32 + ty*4 + i - 4));
      float4 r; r.x=acc[i][0]; r.y=acc[i][1]; r.z=acc[i][2]; r.w=acc[i][3];
      *(float4*)&C[(size_t)row*N + n] = r;
    }
  }
}

// ---------------- causal depthwise conv + silu gating --------
__global__ void k_conv(const float* __restrict__ u, const float* __restrict__ g,
                       const float* __restrict__ cw, const float* __restrict__ cb,
                       float* __restrict__ hh){
  int idx = blockIdx.x*256 + threadIdx.x;
  int c  = idx % DIM;
  int bt = idx / DIM;
  int t  = bt % TT;
  float acc = cb[c];
  #pragma unroll
  for (int j = 0; j < KW; ++j){
    int dt_ = j - (KW-1);
    if (t + dt_ >= 0) acc = fmaf(u[(bt + dt_)*DIM + c], cw[c*KW + j], acc);
  }
  float h = siluf(acc);
  hh[idx] = siluf(g[idx]) * h;
}

// ---------------- pack small projection weights into (D, 28) ----------------
__global__ void k_pack(const float* __restrict__ Wg, const float* __restrict__ Wb,
                       const float* __restrict__ Wa, const float* __restrict__ Wbl,
                       float* __restrict__ Wp){
  int d = blockIdx.x;
  int j = threadIdx.x;
  if (j >= 28) return;
  float v;
  if (j < 4)        v = Wg[d*HH + j];
  else if (j < 12){ int m=(j-4)>>2, h=(j-4)&3;  v = Wb[(m*DD + d)*HH + h]; }
  else if (j < 20){ int m=(j-12)>>2, h=(j-12)&3; v = Wa[(m*DD + d)*HH + h]; }
  else              v = Wbl[d*(HH*MM) + (j-20)];
  Wp[d*28 + j] = v;
}

// ---------------- rk normalization ----------
__global__ void k_rk(const float* __restrict__ y, float* __restrict__ rkb){
  int blk = blockIdx.x;
  int lane = threadIdx.x;
  int row = blk >> 2, h = blk & 3;
  float v = y[row*DD + h*HDIM + lane];
  float ss = v*v;
  #pragma unroll
  for (int o = 32; o > 0; o >>= 1) ss += __shfl_xor(ss, o, 64);
  float nrm = fmaxf(sqrtf(ss), 1e-12f);
  rkb[row*DD + h*HDIM + lane] = v / nrm;
}

// ---------------- precompute scan scalars ----------
__global__ void k_scal(const float* __restrict__ proj, const float* __restrict__ A_log,
                       const float* __restrict__ dtb, float* __restrict__ scal){
  int i = blockIdx.x*256 + threadIdx.x;
  int mh = i & 7;
  int row = i >> 3;
  int m = mh >> 2, h = mh & 3;
  const float* pv = proj + (size_t)row*28;
  float gs  = sigf(pv[h]);
  float btv = sigf(pv[4 + m*4 + h]);
  float sp  = pv[12 + m*4 + h] + dtb[m*HH + h];
  sp = (sp > 15.f) ? sp : log1pf(__expf(sp));
  float dc  = __expf(-__expf(A_log[m*HH + h]) * sp);
  float l0 = pv[20 + h*2], l1 = pv[20 + h*2 + 1];
  float mx = fmaxf(l0, l1);
  float e0 = __expf(l0-mx), e1 = __expf(l1-mx);
  float bl = (m ? e1 : e0) / (e0 + e1);
  float4 o; o.x = dc; o.y = btv; o.z = bl*gs; o.w = 0.f;
  *(float4*)&scal[((size_t)row*MM + m)*(HH*4) + h*4] = o;
}

// ---------------- sequential delta-memory scan ----------
// grid = B*H*8 blocks (k-split by 8, m MERGED into the wave), 64 threads.
// Lane bits {0,1,3} = d-octant q; bits {2,4,5} = klocal. S_A/S_B = 8 floats
// each (m=0 / m=1). Both units share the rk/wk register slots (rotate_half
// for m=1 is fma wiring: (-y, x, -w, z)). Two independent dependency chains
// per step interleave in the pipeline -> ILP hides dependent-latency stalls.
// Period-4 rk slot rotation, depth-2 prefetch at step start.

#define SSTEP(T_, RPRV, RCUR, RPF, VA, SA, VB, SB) { \
  const float dcA = SA.x, btA = SA.y, blgA = SA.z; const float vA_ = VA; \
  const float dcB = SB.x, btB = SB.y, blgB = SB.z; const float vB_ = VB; \
  { const int tn_ = ((T_)+2 < 64) ? (T_)+2 : 63; \
    RPF[0] = *(const float4*)&s_rk[p][tn_][dbase + 0]; \
    RPF[1] = *(const float4*)&s_rk[p][tn_][dbase + 4]; \
    VA = s_v[p][tn_][klocal]; \
    VB = s_v[p][tn_][8 + klocal]; \
    SA = *(const float4*)&s_sc[p][tn_][0]; \
    SB = *(const float4*)&s_sc[p][tn_][4]; } \
  const float4 w0_ = RPRV[0], w1_ = RPRV[1]; \
  float ppA0 = S_A[0]*w0_.x;  ppA0 = fmaf(S_A[1], w0_.y, ppA0); \
  ppA0 = fmaf(S_A[2], w0_.z, ppA0); ppA0 = fmaf(S_A[3], w0_.w, ppA0); \
  float ppA1 = S_A[4]*w1_.x;  ppA1 = fmaf(S_A[5], w1_.y, ppA1); \
  ppA1 = fmaf(S_A[6], w1_.z, ppA1); ppA1 = fmaf(S_A[7], w1_.w, ppA1); \
  float ppB0 = S_B[0]*(-w0_.y); ppB0 = fmaf(S_B[1], w0_.x, ppB0); \
  ppB0 = fmaf(S_B[2], -w0_.w, ppB0); ppB0 = fmaf(S_B[3], w0_.z, ppB0); \
  float ppB1 = S_B[4]*(-w1_.y); ppB1 = fmaf(S_B[5], w1_.x, ppB1); \
  ppB1 = fmaf(S_B[6], -w1_.w, ppB1); ppB1 = fmaf(S_B[7], w1_.z, ppB1); \
  float ppA = ppA0 + ppA1, ppB = ppB0 + ppB1; \
  ppA = xor1_add(ppA); ppA = xor2_add(ppA); ppA = xor8_add(ppA); \
  ppB = xor1_add(ppB); ppB = xor2_add(ppB); ppB = xor8_add(ppB); \
  const float errA = (vA_ - dcA*ppA)*btA; \
  const float errB = (vB_ - dcB*ppB)*btB; \
  float rrA0=0.f, rrA1=0.f, rrB0=0.f, rrB1=0.f; \
  _Pragma("unroll") \
  for (int j = 0; j < 2; ++j){ const float4 rp = RPRV[j]; const float4 rc = RCUR[j]; \
    S_A[4*j+0] = fmaf(S_A[4*j+0], dcA, rp.x*errA); rrA0 = fmaf(S_A[4*j+0], rc.x, rrA0); \
    S_A[4*j+1] = fmaf(S_A[4*j+1], dcA, rp.y*errA); rrA1 = fmaf(S_A[4*j+1], rc.y, rrA1); \
    S_A[4*j+2] = fmaf(S_A[4*j+2], dcA, rp.z*errA); rrA0 = fmaf(S_A[4*j+2], rc.z, rrA0); \
    S_A[4*j+3] = fmaf(S_A[4*j+3], dcA, rp.w*errA); rrA1 = fmaf(S_A[4*j+3], rc.w, rrA1); \
    S_B[4*j+0] = fmaf(S_B[4*j+0], dcB, (-rp.y)*errB); rrB0 = fmaf(S_B[4*j+0], -rc.y, rrB0); \
    S_B[4*j+1] = fmaf(S_B[4*j+1], dcB,   rp.x *errB); rrB1 = fmaf(S_B[4*j+1],  rc.x, rrB1); \
    S_B[4*j+2] = fmaf(S_B[4*j+2], dcB, (-rp.w)*errB); rrB0 = fmaf(S_B[4*j+2], -rc.w, rrB0); \
    S_B[4*j+3] = fmaf(S_B[4*j+3], dcB,   rp.z *errB); rrB1 = fmaf(S_B[4*j+3],  rc.z, rrB1); } \
  float rrA = rrA0 + rrA1, rrB = rrB0 + rrB1; \
  rrA = xor1_add(rrA); rrA = xor2_add(rrA); rrA = xor8_add(rrA); \
  rrB = xor1_add(rrB); rrB = xor2_add(rrB); rrB = xor8_add(rrB); \
  if (q == 0){ \
    const size_t ooff = (size_t)(rowchunk + (T_))*DD + h*HDIM + kq*8 + klocal; \
    partA[ooff] = blgA*rrA; \
    partB[ooff] = blgB*rrB; } \
}

__global__ void __launch_bounds__(64) k_scan(const float* __restrict__ vals,
                                             const float* __restrict__ rkb,
                                             const float* __restrict__ scal,
                                             float* __restrict__ partials){
  __shared__ float s_rk[2][64][64];
  __shared__ float s_v [2][64][16];
  __shared__ float s_sc[2][64][8];
  const int bi = blockIdx.x;      // ((b*HH)+h)*8 + kq
  const int kq = bi & 7;
  const int h  = (bi >> 3) & 3;
  const int b  = bi >> 5;
  const int l  = threadIdx.x;
  const int q = (l & 3) | ((l & 8) >> 1);             // bits 0,1,3
  const int klocal = ((l >> 2) & 1) | ((l >> 3) & 6); // bits 2,4,5
  const int dbase = q*8;
  const int rowbase = b*TT;
  float* partA = partials;
  float* partB = partials + (size_t)(BB*TT*DD);

  float S_A[8], S_B[8];
  #pragma unroll
  for (int j = 0; j < 8; ++j){ S_A[j] = 0.f; S_B[j] = 0.f; }
  const float4 Z = make_float4(0.f,0.f,0.f,0.f);
  float4 rb0[2]={Z,Z}, rb1[2]={Z,Z}, rb2[2]={Z,Z}, rb3[2]={Z,Z};
  float vA0=0.f, vA1=0.f, vB0=0.f, vB1=0.f;
  float4 sA0=Z, sA1=Z, sB0=Z, sB1=Z;

  auto stage = [&](int c, int pbuf){
    const int r0g = rowbase + c*64;
    #pragma unroll
    for (int i = 0; i < 16; ++i){
      const float* g = rkb + (size_t)(r0g + i*4 + (l>>4))*DD + h*HDIM + (l&15)*4;
      gl_lds16(g, &s_rk[pbuf][i*4][0]);
    }
    #pragma unroll
    for (int i = 0; i < 4; ++i){
      const float* g = vals + ((size_t)(r0g + i*16 + (l>>2))*MM + ((l>>1)&1))*DD
                       + h*HDIM + kq*8 + (l&1)*4;
      gl_lds16(g, &s_v[pbuf][i*16][0]);
    }
    #pragma unroll
    for (int i = 0; i < 2; ++i){
      const float* g = scal + ((size_t)(r0g + i*32 + (l>>1))*MM + (l&1))*(HH*4) + h*4;
      gl_lds16(g, &s_sc[pbuf][i*32][0]);
    }
  };

  stage(0, 0);
  for (int c = 0; c < TT/64; ++c){
    const int p = c & 1;
    __syncthreads();                 // vmcnt drain: chunk c staged
    if (c + 1 < TT/64) stage(c+1, p^1);
    // prologue: rk slots 0,1; v/sc for steps 0,1 (rb3 = cross-chunk wk)
    rb0[0] = *(const float4*)&s_rk[p][0][dbase]; rb0[1] = *(const float4*)&s_rk[p][0][dbase+4];
    rb1[0] = *(const float4*)&s_rk[p][1][dbase]; rb1[1] = *(const float4*)&s_rk[p][1][dbase+4];
    vA0 = s_v[p][0][klocal]; vA1 = s_v[p][1][klocal];
    vB0 = s_v[p][0][8+klocal]; vB1 = s_v[p][1][8+klocal];
    sA0 = *(const float4*)&s_sc[p][0][0]; sA1 = *(const float4*)&s_sc[p][1][0];
    sB0 = *(const float4*)&s_sc[p][0][4]; sB1 = *(const float4*)&s_sc[p][1][4];
    const int rowchunk = rowbase + c*64;
    for (int tt = 0; tt < 64; tt += 4){
      SSTEP(tt+0, rb3, rb0, rb2, vA0, sA0, vB0, sB0)
      SSTEP(tt+1, rb0, rb1, rb3, vA1, sA1, vB1, sB1)
      SSTEP(tt+2, rb1, rb2, rb0, vA0, sA0, vB0, sB0)
      SSTEP(tt+3, rb2, rb3, rb1, vA1, sA1, vB1, sB1)
    }
  }
}

extern "C" void kernel_launch(void* const* d_in, const int* in_sizes, int n_in,
                              void* d_out, int out_size, void* d_ws, size_t ws_size,
                              hipStream_t stream){
  const int*   ids   = (const int*)d_in[0];
  const float* emb   = (const float*)d_in[1];
  const float* normw = (const float*)d_in[2];
  const float* Wup   = (const float*)d_in[3];
  const float* Wgate = (const float*)d_in[4];
  const float* Wdown = (const float*)d_in[5];
  const float* convw = (const float*)d_in[6];
  const float* convb = (const float*)d_in[7];
  const float* Wv    = (const float*)d_in[8];
  const float* Wg    = (const float*)d_in[9];
  const float* Wb    = (const float*)d_in[10];
  const float* Wa    = (const float*)d_in[11];
  const float* A_log = (const float*)d_in[12];
  const float* dtb   = (const float*)d_in[13];
  const float* Wbl   = (const float*)d_in[14];
  const float* Wout  = (const float*)d_in[15];
  const float* fnw   = (const float*)d_in[16];
  float* out = (float*)d_out;

  const int ROWS = BB*TT;              // 4096
  const size_t MEG = 1u << 20;
  float* ws   = (float*)d_ws;
  float* x    = ws;                    // 1M
  float* nx   = x    + MEG;            // 1M
  float* big1 = nx   + MEG;            // 2M : u, then vals
  float* big2 = big1 + 2*MEG;          // 2M : g/hh, then partials
  float* y    = big2 + 2*MEG;          // 1M
  float* proj = y    + MEG;            // 128K
  float* rkb  = proj + (1u<<17);       // 1M
  float* Wp   = rkb  + MEG;            // 8K
  float* scal = Wp   + 8192;           // 128K

  k_embed<<<ROWS, DD, 0, stream>>>(ids, emb, x);

  for (int l = 0; l < LL; ++l){
    k_rmsnorm<<<ROWS, 64, 0, stream>>>(x, normw + l*DD, nx);
    float* u = big1; float* g = big2;
    k_gemm_bf<false><<<dim3(DIM/64, ROWS/64), 256, 0, stream>>>(nx, Wup + (size_t)l*DD*DIM, u, DIM, DD);
    k_gemm_bf<false><<<dim3(DIM/64, ROWS/64), 256, 0, stream>>>(nx, Wgate + (size_t)l*DD*DIM, g, DIM, DD);
    k_conv<<<(ROWS*DIM)/256, 256, 0, stream>>>(u, g, convw + l*DIM*KW, convb + l*DIM, g);
    k_gemm_bf<false><<<dim3(DD/64, ROWS/64), 256, 0, stream>>>(g, Wdown + (size_t)l*DIM*DD, y, DD, DIM);
    float* vals = big1;
    k_gemm_bf<false><<<dim3((MM*DD)/64, ROWS/64), 256, 0, stream>>>(y, Wv + (size_t)l*DD*MM*DD, vals, MM*DD, DD);
    k_pack<<<DD, 32, 0, stream>>>(Wg + l*DD*HH, Wb + l*MM*DD*HH, Wa + l*MM*DD*HH,
                                  Wbl + l*DD*HH*MM, Wp);
    k_gemm<false><<<dim3(1, ROWS/64), 128, 0, stream>>>(y, Wp, proj, 28, DD);
    k_scal<<<(ROWS*MM*HH)/256, 256, 0, stream>>>(proj, A_log + l*MM*HH, dtb + l*MM*HH, scal);
    k_rk<<<ROWS*HH, 64, 0, stream>>>(y, rkb);
    k_scan<<<BB*HH*8, 64, 0, stream>>>(vals, rkb, scal, big2);
    // fused: x += y + (p0+p1)@Wout
    k_gemm_wout<<<dim3(DD/64, ROWS/64), 256, 0, stream>>>(big2, big2 + MEG,
                                                          Wout + (size_t)l*DD*DD, y, x);
  }

  k_rmsnorm<<<ROWS, 64, 0, stream>>>(x, fnw, nx);
  k_gemm_bf<true><<<dim3((VV+63)/64, ROWS/64), 256, 0, stream>>>(nx, emb, out, VV, DD);
}

// Round 10
// 385.827 us; speedup vs baseline: 1.3202x; 1.3202x over previous
//
#include <hip/hip_runtime.h>
#include <math.h>

#define BB 8
#define TT 512
#define DD 256
#define DIM 512
#define KW 4
#define MM 2
#define HH 4
#define HDIM 64
#define LL 2
#define VV 272

typedef __attribute__((ext_vector_type(8))) short bf16x8;
typedef __attribute__((ext_vector_type(4))) float f32x4;

__device__ __forceinline__ float sigf(float x){ return 1.f/(1.f+__expf(-x)); }
__device__ __forceinline__ float siluf(float x){ return x/(1.f+__expf(-x)); }

__device__ __forceinline__ unsigned short f2bf(float f){
  unsigned int u = __float_as_uint(f);
  unsigned int r = (u + 0x7FFFu + ((u >> 16) & 1u)) >> 16;
  return (unsigned short)r;
}

// DPP reduces (no DS ops): xor1/xor2 = quad_perm, ror4/ror8 = row rotate.
__device__ __forceinline__ float xor1_add(float x){
  int y = __builtin_amdgcn_update_dpp(0, __float_as_int(x), 0xB1, 0xF, 0xF, true);
  return x + __int_as_float(y);
}
__device__ __forceinline__ float xor2_add(float x){
  int y = __builtin_amdgcn_update_dpp(0, __float_as_int(x), 0x4E, 0xF, 0xF, true);
  return x + __int_as_float(y);
}
__device__ __forceinline__ float xor8_add(float x){
  int y = __builtin_amdgcn_update_dpp(0, __float_as_int(x), 0x128, 0xF, 0xF, true);
  return x + __int_as_float(y);
}
__device__ __forceinline__ float ror4_add(float x){
  int y = __builtin_amdgcn_update_dpp(0, __float_as_int(x), 0x124, 0xF, 0xF, true);
  return x + __int_as_float(y);
}
__device__ __forceinline__ float ror8_add(float x){
  int y = __builtin_amdgcn_update_dpp(0, __float_as_int(x), 0x128, 0xF, 0xF, true);
  return x + __int_as_float(y);
}

// async global->LDS, 16B per lane. LDS dest is wave-uniform base + lane*16.
__device__ __forceinline__ void gl_lds16(const float* g, float* l){
  __builtin_amdgcn_global_load_lds(
      (const __attribute__((address_space(1))) unsigned int*)g,
      (__attribute__((address_space(3))) unsigned int*)l,
      16, 0, 0);
}

// ---------------- embedding gather ----------------
__global__ void k_embed(const int* __restrict__ ids, const float* __restrict__ emb,
                        float* __restrict__ x){
  int row = blockIdx.x;
  int d = threadIdx.x;
  x[row*DD + d] = emb[ids[row]*DD + d];
}

// ---------------- rmsnorm (row of 256), 1 wave/row ----------------
__global__ void k_rmsnorm(const float* __restrict__ in, const float* __restrict__ w,
                          float* __restrict__ out){
  int row = blockIdx.x;
  int l = threadIdx.x;             // 64
  float4 v = *(const float4*)&in[row*DD + l*4];
  float ss = v.x*v.x + v.y*v.y + v.z*v.z + v.w*v.w;
  #pragma unroll
  for (int o = 32; o > 0; o >>= 1) ss += __shfl_xor(ss, o, 64);
  float sc = rsqrtf(ss*(1.f/DD) + 1e-6f);
  float4 wv = *(const float4*)&w[l*4];
  float4 r;
  r.x = v.x*sc*wv.x; r.y = v.y*sc*wv.y; r.z = v.z*sc*wv.z; r.w = v.w*sc*wv.w;
  *(float4*)&out[row*DD + l*4] = r;
}

// ---------------- bf16 MFMA GEMM: C[4096,N] = A[4096,K] @ B ----------------
template<bool BT>
__global__ void __launch_bounds__(256) k_gemm_bf(const float* __restrict__ A,
                                                 const float* __restrict__ B,
                                                 float* __restrict__ C, int N, int K){
  __shared__ unsigned short as[64][88];
  __shared__ unsigned short bs[64][88];
  const int tid = threadIdx.x;
  const int w = tid >> 6, l = tid & 63;
  const int m0 = blockIdx.y*64, n0 = blockIdx.x*64;
  f32x4 acc[4] = {};
  for (int k0 = 0; k0 < K; k0 += 64){
    { int ar = tid >> 2, ac = (tid & 3)*16;
      #pragma unroll
      for (int j = 0; j < 4; ++j){
        float4 a = *(const float4*)&A[(size_t)(m0+ar)*K + k0 + ac + j*4];
        ushort4 u = make_ushort4(f2bf(a.x), f2bf(a.y), f2bf(a.z), f2bf(a.w));
        *(ushort4*)&as[ar][ac + j*4] = u;
      }
    }
    if (!BT){
      int kr = tid >> 2, nc = (tid & 3)*16;
      #pragma unroll
      for (int j = 0; j < 4; ++j){
        int n = n0 + nc + j*4;
        float4 bv = make_float4(0.f,0.f,0.f,0.f);
        if (n < N) bv = *(const float4*)&B[(size_t)(k0+kr)*N + n];
        bs[nc+j*4+0][kr] = f2bf(bv.x);
        bs[nc+j*4+1][kr] = f2bf(bv.y);
        bs[nc+j*4+2][kr] = f2bf(bv.z);
        bs[nc+j*4+3][kr] = f2bf(bv.w);
      }
    } else {
      int nr = tid >> 2, kc = (tid & 3)*16;
      int n = n0 + nr;
      #pragma unroll
      for (int j = 0; j < 4; ++j){
        float4 bv = make_float4(0.f,0.f,0.f,0.f);
        if (n < N) bv = *(const float4*)&B[(size_t)n*K + k0 + kc + j*4];
        ushort4 u = make_ushort4(f2bf(bv.x), f2bf(bv.y), f2bf(bv.z), f2bf(bv.w));
        *(ushort4*)&bs[nr][kc + j*4] = u;
      }
    }
    __syncthreads();
    const int mr = w*16 + (l & 15);
    const int kb = (l >> 4)*8;
    #pragma unroll
    for (int kc2 = 0; kc2 < 2; ++kc2){
      bf16x8 af = *(const bf16x8*)&as[mr][kc2*32 + kb];
      #pragma unroll
      for (int nt = 0; nt < 4; ++nt){
        bf16x8 bfr = *(const bf16x8*)&bs[nt*16 + (l & 15)][kc2*32 + kb];
        acc[nt] = __builtin_amdgcn_mfma_f32_16x16x32_bf16(af, bfr, acc[nt], 0, 0, 0);
      }
    }
    __syncthreads();
  }
  #pragma unroll
  for (int nt = 0; nt < 4; ++nt){
    int col = n0 + nt*16 + (l & 15);
    if (col < N){
      #pragma unroll
      for (int r = 0; r < 4; ++r){
        int row = m0 + w*16 + (l >> 4)*4 + r;
        C[(size_t)row*N + col] = acc[nt][r];
      }
    }
  }
}

// ---- dual GEMM: Cu = A@Bu, Cg = A@Bg (shared A staging), N = DIM, K = DD ----
__global__ void __launch_bounds__(256) k_gemm_up(const float* __restrict__ A,
                                                 const float* __restrict__ Bu,
                                                 const float* __restrict__ Bg,
                                                 float* __restrict__ Cu,
                                                 float* __restrict__ Cg){
  __shared__ unsigned short as[64][88];
  __shared__ unsigned short bu[64][88];
  __shared__ unsigned short bg[64][88];
  const int tid = threadIdx.x;
  const int w = tid >> 6, l = tid & 63;
  const int m0 = blockIdx.y*64, n0 = blockIdx.x*64;
  f32x4 accu[4] = {}; f32x4 accg[4] = {};
  for (int k0 = 0; k0 < DD; k0 += 64){
    { int ar = tid >> 2, ac = (tid & 3)*16;
      #pragma unroll
      for (int j = 0; j < 4; ++j){
        float4 a = *(const float4*)&A[(size_t)(m0+ar)*DD + k0 + ac + j*4];
        ushort4 u = make_ushort4(f2bf(a.x), f2bf(a.y), f2bf(a.z), f2bf(a.w));
        *(ushort4*)&as[ar][ac + j*4] = u;
      }
    }
    { int kr = tid >> 2, nc = (tid & 3)*16;
      #pragma unroll
      for (int j = 0; j < 4; ++j){
        int n = n0 + nc + j*4;
        float4 b0 = *(const float4*)&Bu[(size_t)(k0+kr)*DIM + n];
        bu[nc+j*4+0][kr] = f2bf(b0.x);
        bu[nc+j*4+1][kr] = f2bf(b0.y);
        bu[nc+j*4+2][kr] = f2bf(b0.z);
        bu[nc+j*4+3][kr] = f2bf(b0.w);
        float4 b1 = *(const float4*)&Bg[(size_t)(k0+kr)*DIM + n];
        bg[nc+j*4+0][kr] = f2bf(b1.x);
        bg[nc+j*4+1][kr] = f2bf(b1.y);
        bg[nc+j*4+2][kr] = f2bf(b1.z);
        bg[nc+j*4+3][kr] = f2bf(b1.w);
      }
    }
    __syncthreads();
    const int mr = w*16 + (l & 15);
    const int kb = (l >> 4)*8;
    #pragma unroll
    for (int kc2 = 0; kc2 < 2; ++kc2){
      bf16x8 af = *(const bf16x8*)&as[mr][kc2*32 + kb];
      #pragma unroll
      for (int nt = 0; nt < 4; ++nt){
        bf16x8 b0 = *(const bf16x8*)&bu[nt*16 + (l & 15)][kc2*32 + kb];
        accu[nt] = __builtin_amdgcn_mfma_f32_16x16x32_bf16(af, b0, accu[nt], 0, 0, 0);
        bf16x8 b1 = *(const bf16x8*)&bg[nt*16 + (l & 15)][kc2*32 + kb];
        accg[nt] = __builtin_amdgcn_mfma_f32_16x16x32_bf16(af, b1, accg[nt], 0, 0, 0);
      }
    }
    __syncthreads();
  }
  #pragma unroll
  for (int nt = 0; nt < 4; ++nt){
    int col = n0 + nt*16 + (l & 15);
    #pragma unroll
    for (int r = 0; r < 4; ++r){
      int row = m0 + w*16 + (l >> 4)*4 + r;
      Cu[(size_t)row*DIM + col] = accu[nt][r];
      Cg[(size_t)row*DIM + col] = accg[nt][r];
    }
  }
}

// ---- Wout GEMM with fused comb (A = p0+p1) and resid (x += y + A@Wout) ----
__global__ void __launch_bounds__(256) k_gemm_wout(const float* __restrict__ p0,
                                                   const float* __restrict__ p1,
                                                   const float* __restrict__ B,
                                                   const float* __restrict__ y,
                                                   float* __restrict__ x){
  __shared__ unsigned short as[64][88];
  __shared__ unsigned short bs[64][88];
  const int tid = threadIdx.x;
  const int w = tid >> 6, l = tid & 63;
  const int m0 = blockIdx.y*64, n0 = blockIdx.x*64;
  f32x4 acc[4] = {};
  for (int k0 = 0; k0 < DD; k0 += 64){
    { int ar = tid >> 2, ac = (tid & 3)*16;
      #pragma unroll
      for (int j = 0; j < 4; ++j){
        size_t off = (size_t)(m0+ar)*DD + k0 + ac + j*4;
        float4 a = *(const float4*)&p0[off];
        float4 b = *(const float4*)&p1[off];
        a.x += b.x; a.y += b.y; a.z += b.z; a.w += b.w;
        ushort4 u = make_ushort4(f2bf(a.x), f2bf(a.y), f2bf(a.z), f2bf(a.w));
        *(ushort4*)&as[ar][ac + j*4] = u;
      }
    }
    { int kr = tid >> 2, nc = (tid & 3)*16;
      #pragma unroll
      for (int j = 0; j < 4; ++j){
        float4 bv = *(const float4*)&B[(size_t)(k0+kr)*DD + n0 + nc + j*4];
        bs[nc+j*4+0][kr] = f2bf(bv.x);
        bs[nc+j*4+1][kr] = f2bf(bv.y);
        bs[nc+j*4+2][kr] = f2bf(bv.z);
        bs[nc+j*4+3][kr] = f2bf(bv.w);
      }
    }
    __syncthreads();
    const int mr = w*16 + (l & 15);
    const int kb = (l >> 4)*8;
    #pragma unroll
    for (int kc2 = 0; kc2 < 2; ++kc2){
      bf16x8 af = *(const bf16x8*)&as[mr][kc2*32 + kb];
      #pragma unroll
      for (int nt = 0; nt < 4; ++nt){
        bf16x8 bfr = *(const bf16x8*)&bs[nt*16 + (l & 15)][kc2*32 + kb];
        acc[nt] = __builtin_amdgcn_mfma_f32_16x16x32_bf16(af, bfr, acc[nt], 0, 0, 0);
      }
    }
    __syncthreads();
  }
  #pragma unroll
  for (int nt = 0; nt < 4; ++nt){
    int col = n0 + nt*16 + (l & 15);
    #pragma unroll
    for (int r = 0; r < 4; ++r){
      int row = m0 + w*16 + (l >> 4)*4 + r;
      size_t off = (size_t)row*DD + col;
      x[off] = x[off] + y[off] + acc[nt][r];
    }
  }
}

// ---------------- causal depthwise conv + silu gating --------
__global__ void k_conv(const float* __restrict__ u, const float* __restrict__ g,
                       const float* __restrict__ cw, const float* __restrict__ cb,
                       float* __restrict__ hh){
  int idx = blockIdx.x*256 + threadIdx.x;
  int c  = idx % DIM;
  int bt = idx / DIM;
  int t  = bt % TT;
  float acc = cb[c];
  #pragma unroll
  for (int j = 0; j < KW; ++j){
    int dt_ = j - (KW-1);
    if (t + dt_ >= 0) acc = fmaf(u[(bt + dt_)*DIM + c], cw[c*KW + j], acc);
  }
  float h = siluf(acc);
  hh[idx] = siluf(g[idx]) * h;
}

// ---- fused: proj(small GEMM w/ packed weights) + scal + rk-normalize ----
// grid = ROWS/4 blocks x 256 threads (4 waves, 1 row each).
__global__ void __launch_bounds__(256) k_fused(const float* __restrict__ y,
    const float* __restrict__ Wg, const float* __restrict__ Wb,
    const float* __restrict__ Wa, const float* __restrict__ Wbl,
    const float* __restrict__ A_log, const float* __restrict__ dtb,
    float* __restrict__ rkb, float* __restrict__ scal){
  __shared__ float s_y[4][260];
  __shared__ float s_p[4][32];
  const int wv = threadIdx.x >> 6, l = threadIdx.x & 63;
  const int row = blockIdx.x*4 + wv;

  // load y row; stash in LDS for the proj dot
  float4 yv = *(const float4*)&y[(size_t)row*DD + l*4];
  *(float4*)&s_y[wv][l*4] = yv;

  // rk: per-h norm (h = l>>4 group of 16 lanes, 64 elems)
  float ss = yv.x*yv.x + yv.y*yv.y + yv.z*yv.z + yv.w*yv.w;
  ss = xor1_add(ss); ss = xor2_add(ss);        // quad sums
  ss = ror4_add(ss); ss = ror8_add(ss);        // full 16-lane sum
  float inv = 1.f / fmaxf(sqrtf(ss), 1e-12f);
  float4 rv; rv.x = yv.x*inv; rv.y = yv.y*inv; rv.z = yv.z*inv; rv.w = yv.w*inv;
  *(float4*)&rkb[(size_t)row*DD + l*4] = rv;

  __syncthreads();

  // proj dot: lane j<28 computes sum_k y[k] * W_j[k] via per-lane base+stride
  const int j = (l < 28) ? l : 27;
  const float* wp; int stride;
  if (j < 4){ wp = Wg + j; stride = HH; }
  else if (j < 12){ int m=(j-4)>>2, h=(j-4)&3; wp = Wb + (size_t)m*DD*HH + h; stride = HH; }
  else if (j < 20){ int m=(j-12)>>2, h=(j-12)&3; wp = Wa + (size_t)m*DD*HH + h; stride = HH; }
  else { wp = Wbl + (j-20); stride = HH*MM; }
  float a0=0.f,a1=0.f,a2=0.f,a3=0.f;
  #pragma unroll 4
  for (int k = 0; k < DD; k += 4){
    a0 = fmaf(s_y[wv][k+0], wp[(k+0)*stride], a0);
    a1 = fmaf(s_y[wv][k+1], wp[(k+1)*stride], a1);
    a2 = fmaf(s_y[wv][k+2], wp[(k+2)*stride], a2);
    a3 = fmaf(s_y[wv][k+3], wp[(k+3)*stride], a3);
  }
  if (l < 28) s_p[wv][l] = (a0+a1)+(a2+a3);

  __syncthreads();

  // scal epilogue: lanes 0..7 = (m = l>>2, h = l&3)
  if (l < 8){
    int m = l >> 2, h = l & 3;
    float gs  = sigf(s_p[wv][h]);
    float btv = sigf(s_p[wv][4 + m*4 + h]);
    float sp  = s_p[wv][12 + m*4 + h] + dtb[m*HH + h];
    sp = (sp > 15.f) ? sp : log1pf(__expf(sp));
    float dc  = __expf(-__expf(A_log[m*HH + h]) * sp);
    float l0 = s_p[wv][20 + h*2], l1 = s_p[wv][20 + h*2 + 1];
    float mx = fmaxf(l0, l1);
    float e0 = __expf(l0-mx), e1 = __expf(l1-mx);
    float bl = (m ? e1 : e0) / (e0 + e1);
    float4 o; o.x = dc; o.y = btv; o.z = bl*gs; o.w = 0.f;
    *(float4*)&scal[((size_t)row*MM + m)*(HH*4) + h*4] = o;
  }
}

// ---------------- sequential delta-memory scan (R7 version) ----------
// grid = B*H*M*8 blocks (k-split by 8), 64 threads = 1 wave.
// Lane bits {0,1,3} = d-octant q (8 d each, S[8]/lane); bits {2,4,5} = klocal.
// d-reduce = xor1 + xor2 + xor8, all DPP. Depth-2 register prefetch at step
// start; period-4 rk slot rotation; chunk-of-64 LDS staging via global_load_lds.

#define SSTEP(T_, WK, RK, PF, VB, SB) { \
  const float dc = SB.x, btv = SB.y, blg = SB.z; \
  const float v = VB; \
  { const int tn_ = ((T_)+2 < 64) ? (T_)+2 : 63; \
    PF[0] = *(const float4*)&s_rk[p][tn_][dbase + 0]; \
    PF[1] = *(const float4*)&s_rk[p][tn_][dbase + 4]; \
    VB = s_v[p][tn_][klocal]; \
    SB = *(const float4*)&s_sc[p][tn_][0]; } \
  float pp0=0.f,pp1=0.f; \
  { const float4 r0 = WK[0], r1 = WK[1]; \
    if (ROT == 0){ \
      pp0 = fmaf(S[0], r0.x, pp0); pp0 = fmaf(S[1], r0.y, pp0); \
      pp0 = fmaf(S[2], r0.z, pp0); pp0 = fmaf(S[3], r0.w, pp0); \
      pp1 = fmaf(S[4], r1.x, pp1); pp1 = fmaf(S[5], r1.y, pp1); \
      pp1 = fmaf(S[6], r1.z, pp1); pp1 = fmaf(S[7], r1.w, pp1); \
    } else { \
      pp0 = fmaf(S[0], -r0.y, pp0); pp0 = fmaf(S[1], r0.x, pp0); \
      pp0 = fmaf(S[2], -r0.w, pp0); pp0 = fmaf(S[3], r0.z, pp0); \
      pp1 = fmaf(S[4], -r1.y, pp1); pp1 = fmaf(S[5], r1.x, pp1); \
      pp1 = fmaf(S[6], -r1.w, pp1); pp1 = fmaf(S[7], r1.z, pp1); } } \
  float pp = pp0 + pp1; \
  pp = xor1_add(pp); pp = xor2_add(pp); pp = xor8_add(pp); \
  const float err = (v - dc*pp)*btv; \
  float rr0=0.f,rr1=0.f; \
  _Pragma("unroll") \
  for (int jj = 0; jj < 2; ++jj){ const float4 rp = WK[jj]; const float4 rc = RK[jj]; \
    float w0,w1,w2,w3,c0,c1,c2,c3; \
    if (ROT == 0){ w0=rp.x; w1=rp.y; w2=rp.z; w3=rp.w; c0=rc.x; c1=rc.y; c2=rc.z; c3=rc.w; } \
    else { w0=-rp.y; w1=rp.x; w2=-rp.w; w3=rp.z; c0=-rc.y; c1=rc.x; c2=-rc.w; c3=rc.z; } \
    S[4*jj+0] = fmaf(S[4*jj+0], dc, w0*err); rr0 = fmaf(S[4*jj+0], c0, rr0); \
    S[4*jj+1] = fmaf(S[4*jj+1], dc, w1*err); rr1 = fmaf(S[4*jj+1], c1, rr1); \
    S[4*jj+2] = fmaf(S[4*jj+2], dc, w2*err); rr0 = fmaf(S[4*jj+2], c2, rr0); \
    S[4*jj+3] = fmaf(S[4*jj+3], dc, w3*err); rr1 = fmaf(S[4*jj+3], c3, rr1); } \
  float rr = rr0 + rr1; \
  rr = xor1_add(rr); rr = xor2_add(rr); rr = xor8_add(rr); \
  if (q == 0) part[(size_t)(rowchunk + (T_))*DD + h*HDIM + kq*8 + klocal] = blg*rr; \
}

template<int ROT>
__device__ __forceinline__ void scan_body(int b, int h, int kq, int l,
    const float* __restrict__ vals, const float* __restrict__ rkb,
    const float* __restrict__ scal, float* __restrict__ part,
    float (*s_rk)[64][64], float (*s_v)[64][8], float (*s_sc)[64][4])
{
  const int q = (l & 3) | ((l & 8) >> 1);             // bits 0,1,3
  const int klocal = ((l >> 2) & 1) | ((l >> 3) & 6); // bits 2,4,5
  const int dbase = q*8;
  const int rowbase = b*TT;

  float S[8];
  #pragma unroll
  for (int j = 0; j < 8; ++j) S[j] = 0.f;
  const float4 Z = make_float4(0.f,0.f,0.f,0.f);
  float4 rb0[2]={Z,Z}, rb1[2]={Z,Z}, rb2[2]={Z,Z}, rb3[2]={Z,Z};
  float vb0 = 0.f, vb1 = 0.f;
  float4 sb0 = Z, sb1 = Z;

  auto stage = [&](int c, int pbuf){
    const int r0 = rowbase + c*64;
    #pragma unroll
    for (int i = 0; i < 16; ++i){
      const float* g = rkb + (size_t)(r0 + i*4 + (l>>4))*DD + h*HDIM + (l&15)*4;
      gl_lds16(g, &s_rk[pbuf][i*4][0]);
    }
    #pragma unroll
    for (int i = 0; i < 2; ++i){
      const float* g = vals + ((size_t)(r0 + i*32 + (l>>1))*MM + ROT)*DD + h*HDIM + kq*8 + (l&1)*4;
      gl_lds16(g, &s_v[pbuf][i*32][0]);
    }
    { const float* g = scal + ((size_t)(r0 + l)*MM + ROT)*(HH*4) + h*4;
      gl_lds16(g, &s_sc[pbuf][0][0]); }
  };

  stage(0, 0);
  for (int c = 0; c < TT/64; ++c){
    const int p = c & 1;
    __syncthreads();                 // vmcnt drain: chunk c staged
    if (c + 1 < TT/64) stage(c+1, p^1);
    rb0[0] = *(const float4*)&s_rk[p][0][dbase]; rb0[1] = *(const float4*)&s_rk[p][0][dbase+4];
    rb1[0] = *(const float4*)&s_rk[p][1][dbase]; rb1[1] = *(const float4*)&s_rk[p][1][dbase+4];
    vb0 = s_v[p][0][klocal]; vb1 = s_v[p][1][klocal];
    sb0 = *(const float4*)&s_sc[p][0][0]; sb1 = *(const float4*)&s_sc[p][1][0];
    const int rowchunk = rowbase + c*64;
    for (int tt = 0; tt < 64; tt += 4){
      SSTEP(tt+0, rb3, rb0, rb2, vb0, sb0)
      SSTEP(tt+1, rb0, rb1, rb3, vb1, sb1)
      SSTEP(tt+2, rb1, rb2, rb0, vb0, sb0)
      SSTEP(tt+3, rb2, rb3, rb1, vb1, sb1)
    }
  }
}

__global__ void __launch_bounds__(64) k_scan(const float* __restrict__ vals,
                                             const float* __restrict__ rkb,
                                             const float* __restrict__ scal,
                                             float* __restrict__ partials){
  __shared__ float s_rk[2][64][64];
  __shared__ float s_v [2][64][8];
  __shared__ float s_sc[2][64][4];
  const int bi = blockIdx.x;      // (((b*HH)+h)*MM + m)*8 + kq
  const int kq = bi & 7;
  const int m  = (bi >> 3) & 1;
  const int h  = (bi >> 4) & 3;
  const int b  = bi >> 6;
  float* part = partials + (size_t)m*(BB*TT*DD);
  if (m == 0) scan_body<0>(b, h, kq, threadIdx.x, vals, rkb, scal, part, s_rk, s_v, s_sc);
  else        scan_body<1>(b, h, kq, threadIdx.x, vals, rkb, scal, part, s_rk, s_v, s_sc);
}

extern "C" void kernel_launch(void* const* d_in, const int* in_sizes, int n_in,
                              void* d_out, int out_size, void* d_ws, size_t ws_size,
                              hipStream_t stream){
  const int*   ids   = (const int*)d_in[0];
  const float* emb   = (const float*)d_in[1];
  const float* normw = (const float*)d_in[2];
  const float* Wup   = (const float*)d_in[3];
  const float* Wgate = (const float*)d_in[4];
  const float* Wdown = (const float*)d_in[5];
  const float* convw = (const float*)d_in[6];
  const float* convb = (const float*)d_in[7];
  const float* Wv    = (const float*)d_in[8];
  const float* Wg    = (const float*)d_in[9];
  const float* Wb    = (const float*)d_in[10];
  const float* Wa    = (const float*)d_in[11];
  const float* A_log = (const float*)d_in[12];
  const float* dtb   = (const float*)d_in[13];
  const float* Wbl   = (const float*)d_in[14];
  const float* Wout  = (const float*)d_in[15];
  const float* fnw   = (const float*)d_in[16];
  float* out = (float*)d_out;

  const int ROWS = BB*TT;              // 4096
  const size_t MEG = 1u << 20;
  float* ws   = (float*)d_ws;
  float* x    = ws;                    // 1M
  float* nx   = x    + MEG;            // 1M
  float* big1 = nx   + MEG;            // 2M : u, then vals
  float* big2 = big1 + 2*MEG;          // 2M : g/hh, then partials
  float* y    = big2 + 2*MEG;          // 1M
  float* rkb  = y    + MEG;            // 1M
  float* scal = rkb  + MEG;            // 128K

  k_embed<<<ROWS, DD, 0, stream>>>(ids, emb, x);

  for (int l = 0; l < LL; ++l){
    k_rmsnorm<<<ROWS, 64, 0, stream>>>(x, normw + l*DD, nx);
    float* u = big1; float* g = big2;
    k_gemm_up<<<dim3(DIM/64, ROWS/64), 256, 0, stream>>>(nx, Wup + (size_t)l*DD*DIM,
                                                         Wgate + (size_t)l*DD*DIM, u, g);
    k_conv<<<(ROWS*DIM)/256, 256, 0, stream>>>(u, g, convw + l*DIM*KW, convb + l*DIM, g);
    k_gemm_bf<false><<<dim3(DD/64, ROWS/64), 256, 0, stream>>>(g, Wdown + (size_t)l*DIM*DD, y, DD, DIM);
    float* vals = big1;
    k_gemm_bf<false><<<dim3((MM*DD)/64, ROWS/64), 256, 0, stream>>>(y, Wv + (size_t)l*DD*MM*DD, vals, MM*DD, DD);
    k_fused<<<ROWS/4, 256, 0, stream>>>(y, Wg + l*DD*HH, Wb + (size_t)l*MM*DD*HH,
                                        Wa + (size_t)l*MM*DD*HH, Wbl + l*DD*HH*MM,
                                        A_log + l*MM*HH, dtb + l*MM*HH, rkb, scal);
    k_scan<<<BB*HH*MM*8, 64, 0, stream>>>(vals, rkb, scal, big2);
    // fused: x += y + (p0+p1)@Wout
    k_gemm_wout<<<dim3(DD/64, ROWS/64), 256, 0, stream>>>(big2, big2 + MEG,
                                                          Wout + (size_t)l*DD*DD, y, x);
  }

  k_rmsnorm<<<ROWS, 64, 0, stream>>>(x, fnw, nx);
  k_gemm_bf<true><<<dim3((VV+63)/64, ROWS/64), 256, 0, stream>>>(nx, emb, out, VV, DD);
}

// Round 11
// 333.419 us; speedup vs baseline: 1.5277x; 1.1572x over previous
//
#include <hip/hip_runtime.h>
#include <math.h>

#define BB 8
#define TT 512
#define DD 256
#define DIM 512
#define KW 4
#define MM 2
#define HH 4
#define HDIM 64
#define LL 2
#define VV 272

typedef __attribute__((ext_vector_type(8))) short bf16x8;
typedef __attribute__((ext_vector_type(4))) float f32x4;

__device__ __forceinline__ float sigf(float x){ return 1.f/(1.f+__expf(-x)); }
__device__ __forceinline__ float siluf(float x){ return x/(1.f+__expf(-x)); }

__device__ __forceinline__ unsigned short f2bf(float f){
  unsigned int u = __float_as_uint(f);
  unsigned int r = (u + 0x7FFFu + ((u >> 16) & 1u)) >> 16;
  return (unsigned short)r;
}

// DPP reduces (no DS ops): xor1/xor2 = quad_perm, ror4/ror8 = row rotate.
__device__ __forceinline__ float xor1_add(float x){
  int y = __builtin_amdgcn_update_dpp(0, __float_as_int(x), 0xB1, 0xF, 0xF, true);
  return x + __int_as_float(y);
}
__device__ __forceinline__ float xor2_add(float x){
  int y = __builtin_amdgcn_update_dpp(0, __float_as_int(x), 0x4E, 0xF, 0xF, true);
  return x + __int_as_float(y);
}
__device__ __forceinline__ float xor8_add(float x){
  int y = __builtin_amdgcn_update_dpp(0, __float_as_int(x), 0x128, 0xF, 0xF, true);
  return x + __int_as_float(y);
}
__device__ __forceinline__ float ror4_add(float x){
  int y = __builtin_amdgcn_update_dpp(0, __float_as_int(x), 0x124, 0xF, 0xF, true);
  return x + __int_as_float(y);
}
__device__ __forceinline__ float ror8_add(float x){
  int y = __builtin_amdgcn_update_dpp(0, __float_as_int(x), 0x128, 0xF, 0xF, true);
  return x + __int_as_float(y);
}

// async global->LDS, 16B per lane. LDS dest is wave-uniform base + lane*16.
__device__ __forceinline__ void gl_lds16(const float* g, float* l){
  __builtin_amdgcn_global_load_lds(
      (const __attribute__((address_space(1))) unsigned int*)g,
      (__attribute__((address_space(3))) unsigned int*)l,
      16, 0, 0);
}

// ---------------- embedding gather ----------------
__global__ void k_embed(const int* __restrict__ ids, const float* __restrict__ emb,
                        float* __restrict__ x){
  int row = blockIdx.x;
  int d = threadIdx.x;
  x[row*DD + d] = emb[ids[row]*DD + d];
}

// ---------------- rmsnorm (row of 256), 1 wave/row ----------------
__global__ void k_rmsnorm(const float* __restrict__ in, const float* __restrict__ w,
                          float* __restrict__ out){
  int row = blockIdx.x;
  int l = threadIdx.x;             // 64
  float4 v = *(const float4*)&in[row*DD + l*4];
  float ss = v.x*v.x + v.y*v.y + v.z*v.z + v.w*v.w;
  #pragma unroll
  for (int o = 32; o > 0; o >>= 1) ss += __shfl_xor(ss, o, 64);
  float sc = rsqrtf(ss*(1.f/DD) + 1e-6f);
  float4 wv = *(const float4*)&w[l*4];
  float4 r;
  r.x = v.x*sc*wv.x; r.y = v.y*sc*wv.y; r.z = v.z*sc*wv.z; r.w = v.w*sc*wv.w;
  *(float4*)&out[row*DD + l*4] = r;
}

// ---------------- bf16 MFMA GEMM: C[4096,N] = A[4096,K] @ B ----------------
template<bool BT>
__global__ void __launch_bounds__(256) k_gemm_bf(const float* __restrict__ A,
                                                 const float* __restrict__ B,
                                                 float* __restrict__ C, int N, int K){
  __shared__ unsigned short as[64][88];
  __shared__ unsigned short bs[64][88];
  const int tid = threadIdx.x;
  const int w = tid >> 6, l = tid & 63;
  const int m0 = blockIdx.y*64, n0 = blockIdx.x*64;
  f32x4 acc[4] = {};
  for (int k0 = 0; k0 < K; k0 += 64){
    { int ar = tid >> 2, ac = (tid & 3)*16;
      #pragma unroll
      for (int j = 0; j < 4; ++j){
        float4 a = *(const float4*)&A[(size_t)(m0+ar)*K + k0 + ac + j*4];
        ushort4 u = make_ushort4(f2bf(a.x), f2bf(a.y), f2bf(a.z), f2bf(a.w));
        *(ushort4*)&as[ar][ac + j*4] = u;
      }
    }
    if (!BT){
      int kr = tid >> 2, nc = (tid & 3)*16;
      #pragma unroll
      for (int j = 0; j < 4; ++j){
        int n = n0 + nc + j*4;
        float4 bv = make_float4(0.f,0.f,0.f,0.f);
        if (n < N) bv = *(const float4*)&B[(size_t)(k0+kr)*N + n];
        bs[nc+j*4+0][kr] = f2bf(bv.x);
        bs[nc+j*4+1][kr] = f2bf(bv.y);
        bs[nc+j*4+2][kr] = f2bf(bv.z);
        bs[nc+j*4+3][kr] = f2bf(bv.w);
      }
    } else {
      int nr = tid >> 2, kc = (tid & 3)*16;
      int n = n0 + nr;
      #pragma unroll
      for (int j = 0; j < 4; ++j){
        float4 bv = make_float4(0.f,0.f,0.f,0.f);
        if (n < N) bv = *(const float4*)&B[(size_t)n*K + k0 + kc + j*4];
        ushort4 u = make_ushort4(f2bf(bv.x), f2bf(bv.y), f2bf(bv.z), f2bf(bv.w));
        *(ushort4*)&bs[nr][kc + j*4] = u;
      }
    }
    __syncthreads();
    const int mr = w*16 + (l & 15);
    const int kb = (l >> 4)*8;
    #pragma unroll
    for (int kc2 = 0; kc2 < 2; ++kc2){
      bf16x8 af = *(const bf16x8*)&as[mr][kc2*32 + kb];
      #pragma unroll
      for (int nt = 0; nt < 4; ++nt){
        bf16x8 bfr = *(const bf16x8*)&bs[nt*16 + (l & 15)][kc2*32 + kb];
        acc[nt] = __builtin_amdgcn_mfma_f32_16x16x32_bf16(af, bfr, acc[nt], 0, 0, 0);
      }
    }
    __syncthreads();
  }
  #pragma unroll
  for (int nt = 0; nt < 4; ++nt){
    int col = n0 + nt*16 + (l & 15);
    if (col < N){
      #pragma unroll
      for (int r = 0; r < 4; ++r){
        int row = m0 + w*16 + (l >> 4)*4 + r;
        C[(size_t)row*N + col] = acc[nt][r];
      }
    }
  }
}

// ---- dual GEMM: Cu = A@Bu, Cg = A@Bg (shared A staging), N = DIM, K = DD ----
__global__ void __launch_bounds__(256) k_gemm_up(const float* __restrict__ A,
                                                 const float* __restrict__ Bu,
                                                 const float* __restrict__ Bg,
                                                 float* __restrict__ Cu,
                                                 float* __restrict__ Cg){
  __shared__ unsigned short as[64][88];
  __shared__ unsigned short bu[64][88];
  __shared__ unsigned short bg[64][88];
  const int tid = threadIdx.x;
  const int w = tid >> 6, l = tid & 63;
  const int m0 = blockIdx.y*64, n0 = blockIdx.x*64;
  f32x4 accu[4] = {}; f32x4 accg[4] = {};
  for (int k0 = 0; k0 < DD; k0 += 64){
    { int ar = tid >> 2, ac = (tid & 3)*16;
      #pragma unroll
      for (int j = 0; j < 4; ++j){
        float4 a = *(const float4*)&A[(size_t)(m0+ar)*DD + k0 + ac + j*4];
        ushort4 u = make_ushort4(f2bf(a.x), f2bf(a.y), f2bf(a.z), f2bf(a.w));
        *(ushort4*)&as[ar][ac + j*4] = u;
      }
    }
    { int kr = tid >> 2, nc = (tid & 3)*16;
      #pragma unroll
      for (int j = 0; j < 4; ++j){
        int n = n0 + nc + j*4;
        float4 b0 = *(const float4*)&Bu[(size_t)(k0+kr)*DIM + n];
        bu[nc+j*4+0][kr] = f2bf(b0.x);
        bu[nc+j*4+1][kr] = f2bf(b0.y);
        bu[nc+j*4+2][kr] = f2bf(b0.z);
        bu[nc+j*4+3][kr] = f2bf(b0.w);
        float4 b1 = *(const float4*)&Bg[(size_t)(k0+kr)*DIM + n];
        bg[nc+j*4+0][kr] = f2bf(b1.x);
        bg[nc+j*4+1][kr] = f2bf(b1.y);
        bg[nc+j*4+2][kr] = f2bf(b1.z);
        bg[nc+j*4+3][kr] = f2bf(b1.w);
      }
    }
    __syncthreads();
    const int mr = w*16 + (l & 15);
    const int kb = (l >> 4)*8;
    #pragma unroll
    for (int kc2 = 0; kc2 < 2; ++kc2){
      bf16x8 af = *(const bf16x8*)&as[mr][kc2*32 + kb];
      #pragma unroll
      for (int nt = 0; nt < 4; ++nt){
        bf16x8 b0 = *(const bf16x8*)&bu[nt*16 + (l & 15)][kc2*32 + kb];
        accu[nt] = __builtin_amdgcn_mfma_f32_16x16x32_bf16(af, b0, accu[nt], 0, 0, 0);
        bf16x8 b1 = *(const bf16x8*)&bg[nt*16 + (l & 15)][kc2*32 + kb];
        accg[nt] = __builtin_amdgcn_mfma_f32_16x16x32_bf16(af, b1, accg[nt], 0, 0, 0);
      }
    }
    __syncthreads();
  }
  #pragma unroll
  for (int nt = 0; nt < 4; ++nt){
    int col = n0 + nt*16 + (l & 15);
    #pragma unroll
    for (int r = 0; r < 4; ++r){
      int row = m0 + w*16 + (l >> 4)*4 + r;
      Cu[(size_t)row*DIM + col] = accu[nt][r];
      Cg[(size_t)row*DIM + col] = accg[nt][r];
    }
  }
}

// ---- Wout GEMM with fused comb (A = p0+p1) and resid (x += y + A@Wout) ----
__global__ void __launch_bounds__(256) k_gemm_wout(const float* __restrict__ p0,
                                                   const float* __restrict__ p1,
                                                   const float* __restrict__ B,
                                                   const float* __restrict__ y,
                                                   float* __restrict__ x){
  __shared__ unsigned short as[64][88];
  __shared__ unsigned short bs[64][88];
  const int tid = threadIdx.x;
  const int w = tid >> 6, l = tid & 63;
  const int m0 = blockIdx.y*64, n0 = blockIdx.x*64;
  f32x4 acc[4] = {};
  for (int k0 = 0; k0 < DD; k0 += 64){
    { int ar = tid >> 2, ac = (tid & 3)*16;
      #pragma unroll
      for (int j = 0; j < 4; ++j){
        size_t off = (size_t)(m0+ar)*DD + k0 + ac + j*4;
        float4 a = *(const float4*)&p0[off];
        float4 b = *(const float4*)&p1[off];
        a.x += b.x; a.y += b.y; a.z += b.z; a.w += b.w;
        ushort4 u = make_ushort4(f2bf(a.x), f2bf(a.y), f2bf(a.z), f2bf(a.w));
        *(ushort4*)&as[ar][ac + j*4] = u;
      }
    }
    { int kr = tid >> 2, nc = (tid & 3)*16;
      #pragma unroll
      for (int j = 0; j < 4; ++j){
        float4 bv = *(const float4*)&B[(size_t)(k0+kr)*DD + n0 + nc + j*4];
        bs[nc+j*4+0][kr] = f2bf(bv.x);
        bs[nc+j*4+1][kr] = f2bf(bv.y);
        bs[nc+j*4+2][kr] = f2bf(bv.z);
        bs[nc+j*4+3][kr] = f2bf(bv.w);
      }
    }
    __syncthreads();
    const int mr = w*16 + (l & 15);
    const int kb = (l >> 4)*8;
    #pragma unroll
    for (int kc2 = 0; kc2 < 2; ++kc2){
      bf16x8 af = *(const bf16x8*)&as[mr][kc2*32 + kb];
      #pragma unroll
      for (int nt = 0; nt < 4; ++nt){
        bf16x8 bfr = *(const bf16x8*)&bs[nt*16 + (l & 15)][kc2*32 + kb];
        acc[nt] = __builtin_amdgcn_mfma_f32_16x16x32_bf16(af, bfr, acc[nt], 0, 0, 0);
      }
    }
    __syncthreads();
  }
  #pragma unroll
  for (int nt = 0; nt < 4; ++nt){
    int col = n0 + nt*16 + (l & 15);
    #pragma unroll
    for (int r = 0; r < 4; ++r){
      int row = m0 + w*16 + (l >> 4)*4 + r;
      size_t off = (size_t)row*DD + col;
      x[off] = x[off] + y[off] + acc[nt][r];
    }
  }
}

// ---------------- causal depthwise conv + silu gating --------
__global__ void k_conv(const float* __restrict__ u, const float* __restrict__ g,
                       const float* __restrict__ cw, const float* __restrict__ cb,
                       float* __restrict__ hh){
  int idx = blockIdx.x*256 + threadIdx.x;
  int c  = idx % DIM;
  int bt = idx / DIM;
  int t  = bt % TT;
  float acc = cb[c];
  #pragma unroll
  for (int j = 0; j < KW; ++j){
    int dt_ = j - (KW-1);
    if (t + dt_ >= 0) acc = fmaf(u[(bt + dt_)*DIM + c], cw[c*KW + j], acc);
  }
  float h = siluf(acc);
  hh[idx] = siluf(g[idx]) * h;
}

// ---- fused: proj(small GEMM w/ packed weights) + scal + rk-normalize ----
// grid = ROWS/4 blocks x 256 threads (4 waves, 1 row each).
__global__ void __launch_bounds__(256) k_fused(const float* __restrict__ y,
    const float* __restrict__ Wg, const float* __restrict__ Wb,
    const float* __restrict__ Wa, const float* __restrict__ Wbl,
    const float* __restrict__ A_log, const float* __restrict__ dtb,
    float* __restrict__ rkb, float* __restrict__ scal){
  __shared__ float s_y[4][260];
  __shared__ float s_p[4][32];
  const int wv = threadIdx.x >> 6, l = threadIdx.x & 63;
  const int row = blockIdx.x*4 + wv;

  float4 yv = *(const float4*)&y[(size_t)row*DD + l*4];
  *(float4*)&s_y[wv][l*4] = yv;

  // rk: per-h norm (h = l>>4 group of 16 lanes, 64 elems)
  float ss = yv.x*yv.x + yv.y*yv.y + yv.z*yv.z + yv.w*yv.w;
  ss = xor1_add(ss); ss = xor2_add(ss);
  ss = ror4_add(ss); ss = ror8_add(ss);
  float inv = 1.f / fmaxf(sqrtf(ss), 1e-12f);
  float4 rv; rv.x = yv.x*inv; rv.y = yv.y*inv; rv.z = yv.z*inv; rv.w = yv.w*inv;
  *(float4*)&rkb[(size_t)row*DD + l*4] = rv;

  __syncthreads();

  const int j = (l < 28) ? l : 27;
  const float* wp; int stride;
  if (j < 4){ wp = Wg + j; stride = HH; }
  else if (j < 12){ int m=(j-4)>>2, h=(j-4)&3; wp = Wb + (size_t)m*DD*HH + h; stride = HH; }
  else if (j < 20){ int m=(j-12)>>2, h=(j-12)&3; wp = Wa + (size_t)m*DD*HH + h; stride = HH; }
  else { wp = Wbl + (j-20); stride = HH*MM; }
  float a0=0.f,a1=0.f,a2=0.f,a3=0.f;
  #pragma unroll 4
  for (int k = 0; k < DD; k += 4){
    a0 = fmaf(s_y[wv][k+0], wp[(k+0)*stride], a0);
    a1 = fmaf(s_y[wv][k+1], wp[(k+1)*stride], a1);
    a2 = fmaf(s_y[wv][k+2], wp[(k+2)*stride], a2);
    a3 = fmaf(s_y[wv][k+3], wp[(k+3)*stride], a3);
  }
  if (l < 28) s_p[wv][l] = (a0+a1)+(a2+a3);

  __syncthreads();

  if (l < 8){
    int m = l >> 2, h = l & 3;
    float gs  = sigf(s_p[wv][h]);
    float btv = sigf(s_p[wv][4 + m*4 + h]);
    float sp  = s_p[wv][12 + m*4 + h] + dtb[m*HH + h];
    sp = (sp > 15.f) ? sp : log1pf(__expf(sp));
    float dc  = __expf(-__expf(A_log[m*HH + h]) * sp);
    float l0 = s_p[wv][20 + h*2], l1 = s_p[wv][20 + h*2 + 1];
    float mx = fmaxf(l0, l1);
    float e0 = __expf(l0-mx), e1 = __expf(l1-mx);
    float bl = (m ? e1 : e0) / (e0 + e1);
    float4 o; o.x = dc; o.y = btv; o.z = bl*gs; o.w = 0.f;
    *(float4*)&scal[((size_t)row*MM + m)*(HH*4) + h*4] = o;
  }
}

// ---------------- sequential delta-memory scan ----------
// grid = B*H*M*8 blocks (k-split by 8), 64 threads = 1 wave.
// Lane bits {0,1,3} = d-octant q (8 d each, S[8]/lane); bits {2,4,5} = klocal.
// KEY IDENTITY: wk(t+1) = rk(t)  =>  pred(t+1) = <S(t), rk(t)> = read(t).
// So the read-dot rr is carried in a register and reused as next step's pred
// — the pred-dot phase is deleted entirely (halves fma + DPP per step and
// shortens the serial dependency chain).
// Per step: err = (v - dc*rr_carry)*bt; S = dc*S + wk*err; rr = <S, rk>.

#define SSTEP(T_, WK, RK, PF, VB, SB) { \
  const float dc = SB.x, btv = SB.y, blg = SB.z; \
  const float v = VB; \
  { const int tn_ = ((T_)+2 < 64) ? (T_)+2 : 63; \
    PF[0] = *(const float4*)&s_rk[p][tn_][dbase + 0]; \
    PF[1] = *(const float4*)&s_rk[p][tn_][dbase + 4]; \
    VB = s_v[p][tn_][klocal]; \
    SB = *(const float4*)&s_sc[p][tn_][0]; } \
  const float err = (v - dc*rrc)*btv; \
  float rr0=0.f,rr1=0.f; \
  _Pragma("unroll") \
  for (int jj = 0; jj < 2; ++jj){ const float4 rp = WK[jj]; const float4 rc = RK[jj]; \
    float w0,w1,w2,w3,c0,c1,c2,c3; \
    if (ROT == 0){ w0=rp.x; w1=rp.y; w2=rp.z; w3=rp.w; c0=rc.x; c1=rc.y; c2=rc.z; c3=rc.w; } \
    else { w0=-rp.y; w1=rp.x; w2=-rp.w; w3=rp.z; c0=-rc.y; c1=rc.x; c2=-rc.w; c3=rc.z; } \
    S[4*jj+0] = fmaf(S[4*jj+0], dc, w0*err); rr0 = fmaf(S[4*jj+0], c0, rr0); \
    S[4*jj+1] = fmaf(S[4*jj+1], dc, w1*err); rr1 = fmaf(S[4*jj+1], c1, rr1); \
    S[4*jj+2] = fmaf(S[4*jj+2], dc, w2*err); rr0 = fmaf(S[4*jj+2], c2, rr0); \
    S[4*jj+3] = fmaf(S[4*jj+3], dc, w3*err); rr1 = fmaf(S[4*jj+3], c3, rr1); } \
  float rr = rr0 + rr1; \
  rr = xor1_add(rr); rr = xor2_add(rr); rr = xor8_add(rr); \
  rrc = rr; \
  if (q == 0) part[(size_t)(rowchunk + (T_))*DD + h*HDIM + kq*8 + klocal] = blg*rr; \
}

template<int ROT>
__device__ __forceinline__ void scan_body(int b, int h, int kq, int l,
    const float* __restrict__ vals, const float* __restrict__ rkb,
    const float* __restrict__ scal, float* __restrict__ part,
    float (*s_rk)[64][64], float (*s_v)[64][8], float (*s_sc)[64][4])
{
  const int q = (l & 3) | ((l & 8) >> 1);             // bits 0,1,3
  const int klocal = ((l >> 2) & 1) | ((l >> 3) & 6); // bits 2,4,5
  const int dbase = q*8;
  const int rowbase = b*TT;

  float S[8];
  #pragma unroll
  for (int j = 0; j < 8; ++j) S[j] = 0.f;
  const float4 Z = make_float4(0.f,0.f,0.f,0.f);
  float4 rb0[2]={Z,Z}, rb1[2]={Z,Z}, rb2[2]={Z,Z}, rb3[2]={Z,Z};
  float vb0 = 0.f, vb1 = 0.f;
  float4 sb0 = Z, sb1 = Z;
  float rrc = 0.f;    // carried read-dot == next step's pred (S0 = 0 -> 0)

  auto stage = [&](int c, int pbuf){
    const int r0 = rowbase + c*64;
    #pragma unroll
    for (int i = 0; i < 16; ++i){
      const float* g = rkb + (size_t)(r0 + i*4 + (l>>4))*DD + h*HDIM + (l&15)*4;
      gl_lds16(g, &s_rk[pbuf][i*4][0]);
    }
    #pragma unroll
    for (int i = 0; i < 2; ++i){
      const float* g = vals + ((size_t)(r0 + i*32 + (l>>1))*MM + ROT)*DD + h*HDIM + kq*8 + (l&1)*4;
      gl_lds16(g, &s_v[pbuf][i*32][0]);
    }
    { const float* g = scal + ((size_t)(r0 + l)*MM + ROT)*(HH*4) + h*4;
      gl_lds16(g, &s_sc[pbuf][0][0]); }
  };

  stage(0, 0);
  for (int c = 0; c < TT/64; ++c){
    const int p = c & 1;
    __syncthreads();                 // vmcnt drain: chunk c staged
    if (c + 1 < TT/64) stage(c+1, p^1);
    rb0[0] = *(const float4*)&s_rk[p][0][dbase]; rb0[1] = *(const float4*)&s_rk[p][0][dbase+4];
    rb1[0] = *(const float4*)&s_rk[p][1][dbase]; rb1[1] = *(const float4*)&s_rk[p][1][dbase+4];
    vb0 = s_v[p][0][klocal]; vb1 = s_v[p][1][klocal];
    sb0 = *(const float4*)&s_sc[p][0][0]; sb1 = *(const float4*)&s_sc[p][1][0];
    const int rowchunk = rowbase + c*64;
    for (int tt = 0; tt < 64; tt += 4){
      SSTEP(tt+0, rb3, rb0, rb2, vb0, sb0)
      SSTEP(tt+1, rb0, rb1, rb3, vb1, sb1)
      SSTEP(tt+2, rb1, rb2, rb0, vb0, sb0)
      SSTEP(tt+3, rb2, rb3, rb1, vb1, sb1)
    }
  }
}

__global__ void __launch_bounds__(64) k_scan(const float* __restrict__ vals,
                                             const float* __restrict__ rkb,
                                             const float* __restrict__ scal,
                                             float* __restrict__ partials){
  __shared__ float s_rk[2][64][64];
  __shared__ float s_v [2][64][8];
  __shared__ float s_sc[2][64][4];
  const int bi = blockIdx.x;      // (((b*HH)+h)*MM + m)*8 + kq
  const int kq = bi & 7;
  const int m  = (bi >> 3) & 1;
  const int h  = (bi >> 4) & 3;
  const int b  = bi >> 6;
  float* part = partials + (size_t)m*(BB*TT*DD);
  if (m == 0) scan_body<0>(b, h, kq, threadIdx.x, vals, rkb, scal, part, s_rk, s_v, s_sc);
  else        scan_body<1>(b, h, kq, threadIdx.x, vals, rkb, scal, part, s_rk, s_v, s_sc);
}

extern "C" void kernel_launch(void* const* d_in, const int* in_sizes, int n_in,
                              void* d_out, int out_size, void* d_ws, size_t ws_size,
                              hipStream_t stream){
  const int*   ids   = (const int*)d_in[0];
  const float* emb   = (const float*)d_in[1];
  const float* normw = (const float*)d_in[2];
  const float* Wup   = (const float*)d_in[3];
  const float* Wgate = (const float*)d_in[4];
  const float* Wdown = (const float*)d_in[5];
  const float* convw = (const float*)d_in[6];
  const float* convb = (const float*)d_in[7];
  const float* Wv    = (const float*)d_in[8];
  const float* Wg    = (const float*)d_in[9];
  const float* Wb    = (const float*)d_in[10];
  const float* Wa    = (const float*)d_in[11];
  const float* A_log = (const float*)d_in[12];
  const float* dtb   = (const float*)d_in[13];
  const float* Wbl   = (const float*)d_in[14];
  const float* Wout  = (const float*)d_in[15];
  const float* fnw   = (const float*)d_in[16];
  float* out = (float*)d_out;

  const int ROWS = BB*TT;              // 4096
  const size_t MEG = 1u << 20;
  float* ws   = (float*)d_ws;
  float* x    = ws;                    // 1M
  float* nx   = x    + MEG;            // 1M
  float* big1 = nx   + MEG;            // 2M : u, then vals
  float* big2 = big1 + 2*MEG;          // 2M : g/hh, then partials
  float* y    = big2 + 2*MEG;          // 1M
  float* rkb  = y    + MEG;            // 1M
  float* scal = rkb  + MEG;            // 128K

  k_embed<<<ROWS, DD, 0, stream>>>(ids, emb, x);

  for (int l = 0; l < LL; ++l){
    k_rmsnorm<<<ROWS, 64, 0, stream>>>(x, normw + l*DD, nx);
    float* u = big1; float* g = big2;
    k_gemm_up<<<dim3(DIM/64, ROWS/64), 256, 0, stream>>>(nx, Wup + (size_t)l*DD*DIM,
                                                         Wgate + (size_t)l*DD*DIM, u, g);
    k_conv<<<(ROWS*DIM)/256, 256, 0, stream>>>(u, g, convw + l*DIM*KW, convb + l*DIM, g);
    k_gemm_bf<false><<<dim3(DD/64, ROWS/64), 256, 0, stream>>>(g, Wdown + (size_t)l*DIM*DD, y, DD, DIM);
    float* vals = big1;
    k_gemm_bf<false><<<dim3((MM*DD)/64, ROWS/64), 256, 0, stream>>>(y, Wv + (size_t)l*DD*MM*DD, vals, MM*DD, DD);
    k_fused<<<ROWS/4, 256, 0, stream>>>(y, Wg + l*DD*HH, Wb + (size_t)l*MM*DD*HH,
                                        Wa + (size_t)l*MM*DD*HH, Wbl + l*DD*HH*MM,
                                        A_log + l*MM*HH, dtb + l*MM*HH, rkb, scal);
    k_scan<<<BB*HH*MM*8, 64, 0, stream>>>(vals, rkb, scal, big2);
    // fused: x += y + (p0+p1)@Wout
    k_gemm_wout<<<dim3(DD/64, ROWS/64), 256, 0, stream>>>(big2, big2 + MEG,
                                                          Wout + (size_t)l*DD*DD, y, x);
  }

  k_rmsnorm<<<ROWS, 64, 0, stream>>>(x, fnw, nx);
  k_gemm_bf<true><<<dim3((VV+63)/64, ROWS/64), 256, 0, stream>>>(nx, emb, out, VV, DD);
}

// Round 12
// 295.885 us; speedup vs baseline: 1.7215x; 1.1269x over previous
//
#include <hip/hip_runtime.h>
#include <math.h>

#define BB 8
#define TT 512
#define DD 256
#define DIM 512
#define KW 4
#define MM 2
#define HH 4
#define HDIM 64
#define LL 2
#define VV 272

typedef __attribute__((ext_vector_type(8))) short bf16x8;
typedef __attribute__((ext_vector_type(4))) float f32x4;

__device__ __forceinline__ float sigf(float x){ return 1.f/(1.f+__expf(-x)); }
__device__ __forceinline__ float siluf(float x){ return x/(1.f+__expf(-x)); }

__device__ __forceinline__ unsigned short f2bf(float f){
  unsigned int u = __float_as_uint(f);
  unsigned int r = (u + 0x7FFFu + ((u >> 16) & 1u)) >> 16;
  return (unsigned short)r;
}
__device__ __forceinline__ float bf2f(unsigned short s){
  return __uint_as_float(((unsigned int)s) << 16);
}

// DPP reduces (no DS ops)
__device__ __forceinline__ float xor1_add(float x){
  int y = __builtin_amdgcn_update_dpp(0, __float_as_int(x), 0xB1, 0xF, 0xF, true);
  return x + __int_as_float(y);
}
__device__ __forceinline__ float xor2_add(float x){
  int y = __builtin_amdgcn_update_dpp(0, __float_as_int(x), 0x4E, 0xF, 0xF, true);
  return x + __int_as_float(y);
}
__device__ __forceinline__ float xor8_add(float x){
  int y = __builtin_amdgcn_update_dpp(0, __float_as_int(x), 0x128, 0xF, 0xF, true);
  return x + __int_as_float(y);
}
__device__ __forceinline__ float ror4_add(float x){
  int y = __builtin_amdgcn_update_dpp(0, __float_as_int(x), 0x124, 0xF, 0xF, true);
  return x + __int_as_float(y);
}
__device__ __forceinline__ float ror8_add(float x){
  int y = __builtin_amdgcn_update_dpp(0, __float_as_int(x), 0x128, 0xF, 0xF, true);
  return x + __int_as_float(y);
}

// async global->LDS, 16B per lane. LDS dest is wave-uniform base + lane*16.
__device__ __forceinline__ void gl_lds16(const void* g, void* l){
  __builtin_amdgcn_global_load_lds(
      (const __attribute__((address_space(1))) unsigned int*)g,
      (__attribute__((address_space(3))) unsigned int*)l,
      16, 0, 0);
}

// ---------------- weight convert + transpose to bf16 [N][K] ----------------
// wbf layout (ushorts): per layer (589824): upT[512][256] | gateT[512][256] |
// downT[256][512] | wvT[512][256] | woutT[256][256]; then emb[272][256].
#define LWB 589824
__global__ void k_cvt(const float* __restrict__ Wup, const float* __restrict__ Wgate,
                      const float* __restrict__ Wdown, const float* __restrict__ Wv,
                      const float* __restrict__ Wout, const float* __restrict__ emb,
                      unsigned short* __restrict__ wbf){
  int idx = blockIdx.x*256 + threadIdx.x;
  if (idx >= 2*LWB + VV*DD) return;
  float v;
  if (idx < 2*LWB){
    int l = (idx >= LWB) ? 1 : 0;
    int local = idx - l*LWB;
    if (local < 131072){ int n = local>>8, k = local&255;
      v = Wup[(size_t)l*131072 + k*DIM + n]; }
    else if (local < 262144){ local -= 131072; int n = local>>8, k = local&255;
      v = Wgate[(size_t)l*131072 + k*DIM + n]; }
    else if (local < 393216){ local -= 262144; int n = local>>9, k = local&511;
      v = Wdown[(size_t)l*131072 + k*DD + n]; }
    else if (local < 524288){ local -= 393216; int n = local>>8, k = local&255;
      v = Wv[(size_t)l*131072 + k*DIM + n]; }
    else { local -= 524288; int n = local>>8, k = local&255;
      v = Wout[(size_t)l*65536 + k*DD + n]; }
  } else {
    v = emb[idx - 2*LWB];
  }
  wbf[idx] = f2bf(v);
}

// ---------------- embedding gather ----------------
__global__ void k_embed(const int* __restrict__ ids, const float* __restrict__ emb,
                        float* __restrict__ x){
  int row = blockIdx.x;
  int d = threadIdx.x;
  x[row*DD + d] = emb[ids[row]*DD + d];
}

// ---------------- rmsnorm (row of 256) -> bf16 out, 1 wave/row ----------------
__global__ void k_rmsnorm(const float* __restrict__ in, const float* __restrict__ w,
                          unsigned short* __restrict__ out){
  int row = blockIdx.x;
  int l = threadIdx.x;             // 64
  float4 v = *(const float4*)&in[row*DD + l*4];
  float ss = v.x*v.x + v.y*v.y + v.z*v.z + v.w*v.w;
  #pragma unroll
  for (int o = 32; o > 0; o >>= 1) ss += __shfl_xor(ss, o, 64);
  float sc = rsqrtf(ss*(1.f/DD) + 1e-6f);
  float4 wv = *(const float4*)&w[l*4];
  ushort4 r;
  r.x = f2bf(v.x*sc*wv.x); r.y = f2bf(v.y*sc*wv.y);
  r.z = f2bf(v.z*sc*wv.z); r.w = f2bf(v.w*sc*wv.w);
  *(ushort4*)&out[row*DD + l*4] = r;
}

// ------------- bf16 GEMM: C[4096,N] = A[4096,K]@Bt^T, A/Bt bf16 -------------
// A [M][K] bf16 row-major, Bt [N][K] bf16 row-major. 64x64 tile, 4 waves.
// MODE 0: f32 C. MODE 1: bf16 C. MODE 2: both.
template<int MODE>
__global__ void __launch_bounds__(256) k_gemm2(const unsigned short* __restrict__ A,
                                               const unsigned short* __restrict__ Bt,
                                               float* __restrict__ Cf,
                                               unsigned short* __restrict__ Cb,
                                               int N, int K){
  __shared__ unsigned short as[64][72];
  __shared__ unsigned short bs[64][72];
  const int tid = threadIdx.x;
  const int w = tid >> 6, l = tid & 63;
  const int m0 = blockIdx.y*64, n0 = blockIdx.x*64;
  const int ar = tid >> 2, ac = (tid & 3)*16;
  f32x4 acc[4] = {};
  for (int k0 = 0; k0 < K; k0 += 64){
    { const bf16x8* src = (const bf16x8*)&A[(size_t)(m0+ar)*K + k0 + ac];
      *(bf16x8*)&as[ar][ac]   = src[0];
      *(bf16x8*)&as[ar][ac+8] = src[1];
    }
    { int n = n0 + ar;
      bf16x8 z; z = (bf16x8)(short)0;
      bf16x8 b0 = z, b1 = z;
      if (n < N){
        const bf16x8* src = (const bf16x8*)&Bt[(size_t)n*K + k0 + ac];
        b0 = src[0]; b1 = src[1];
      }
      *(bf16x8*)&bs[ar][ac]   = b0;
      *(bf16x8*)&bs[ar][ac+8] = b1;
    }
    __syncthreads();
    const int mr = w*16 + (l & 15);
    const int kb = (l >> 4)*8;
    #pragma unroll
    for (int kc2 = 0; kc2 < 2; ++kc2){
      bf16x8 af = *(const bf16x8*)&as[mr][kc2*32 + kb];
      #pragma unroll
      for (int nt = 0; nt < 4; ++nt){
        bf16x8 bfr = *(const bf16x8*)&bs[nt*16 + (l & 15)][kc2*32 + kb];
        acc[nt] = __builtin_amdgcn_mfma_f32_16x16x32_bf16(af, bfr, acc[nt], 0, 0, 0);
      }
    }
    __syncthreads();
  }
  #pragma unroll
  for (int nt = 0; nt < 4; ++nt){
    int col = n0 + nt*16 + (l & 15);
    if (col < N){
      #pragma unroll
      for (int r = 0; r < 4; ++r){
        int row = m0 + w*16 + (l >> 4)*4 + r;
        if (MODE == 0 || MODE == 2) Cf[(size_t)row*N + col] = acc[nt][r];
        if (MODE == 1 || MODE == 2) Cb[(size_t)row*N + col] = f2bf(acc[nt][r]);
      }
    }
  }
}

// ---- dual GEMM: Cu = A@BuT^T, Cg = A@BgT^T (shared A), N=DIM, K=DD, bf16 ----
__global__ void __launch_bounds__(256) k_gemm_up(const unsigned short* __restrict__ A,
                                                 const unsigned short* __restrict__ But,
                                                 const unsigned short* __restrict__ Bgt,
                                                 unsigned short* __restrict__ Cu,
                                                 unsigned short* __restrict__ Cg){
  __shared__ unsigned short as[64][72];
  __shared__ unsigned short bu[64][72];
  __shared__ unsigned short bg[64][72];
  const int tid = threadIdx.x;
  const int w = tid >> 6, l = tid & 63;
  const int m0 = blockIdx.y*64, n0 = blockIdx.x*64;
  const int ar = tid >> 2, ac = (tid & 3)*16;
  f32x4 accu[4] = {}; f32x4 accg[4] = {};
  for (int k0 = 0; k0 < DD; k0 += 64){
    { const bf16x8* src = (const bf16x8*)&A[(size_t)(m0+ar)*DD + k0 + ac];
      *(bf16x8*)&as[ar][ac]   = src[0];
      *(bf16x8*)&as[ar][ac+8] = src[1];
    }
    { const bf16x8* s0 = (const bf16x8*)&But[(size_t)(n0+ar)*DD + k0 + ac];
      *(bf16x8*)&bu[ar][ac]   = s0[0];
      *(bf16x8*)&bu[ar][ac+8] = s0[1];
      const bf16x8* s1 = (const bf16x8*)&Bgt[(size_t)(n0+ar)*DD + k0 + ac];
      *(bf16x8*)&bg[ar][ac]   = s1[0];
      *(bf16x8*)&bg[ar][ac+8] = s1[1];
    }
    __syncthreads();
    const int mr = w*16 + (l & 15);
    const int kb = (l >> 4)*8;
    #pragma unroll
    for (int kc2 = 0; kc2 < 2; ++kc2){
      bf16x8 af = *(const bf16x8*)&as[mr][kc2*32 + kb];
      #pragma unroll
      for (int nt = 0; nt < 4; ++nt){
        bf16x8 b0 = *(const bf16x8*)&bu[nt*16 + (l & 15)][kc2*32 + kb];
        accu[nt] = __builtin_amdgcn_mfma_f32_16x16x32_bf16(af, b0, accu[nt], 0, 0, 0);
        bf16x8 b1 = *(const bf16x8*)&bg[nt*16 + (l & 15)][kc2*32 + kb];
        accg[nt] = __builtin_amdgcn_mfma_f32_16x16x32_bf16(af, b1, accg[nt], 0, 0, 0);
      }
    }
    __syncthreads();
  }
  #pragma unroll
  for (int nt = 0; nt < 4; ++nt){
    int col = n0 + nt*16 + (l & 15);
    #pragma unroll
    for (int r = 0; r < 4; ++r){
      int row = m0 + w*16 + (l >> 4)*4 + r;
      Cu[(size_t)row*DIM + col] = f2bf(accu[nt][r]);
      Cg[(size_t)row*DIM + col] = f2bf(accg[nt][r]);
    }
  }
}

// ---- Wout GEMM: fused comb (A = p0+p1, f32) + resid (x += y + A@WoutT^T) ----
__global__ void __launch_bounds__(256) k_gemm_wout(const float* __restrict__ p0,
                                                   const float* __restrict__ p1,
                                                   const unsigned short* __restrict__ Bt,
                                                   const float* __restrict__ y,
                                                   float* __restrict__ x){
  __shared__ unsigned short as[64][72];
  __shared__ unsigned short bs[64][72];
  const int tid = threadIdx.x;
  const int w = tid >> 6, l = tid & 63;
  const int m0 = blockIdx.y*64, n0 = blockIdx.x*64;
  const int ar = tid >> 2, ac = (tid & 3)*16;
  f32x4 acc[4] = {};
  for (int k0 = 0; k0 < DD; k0 += 64){
    #pragma unroll
    for (int j = 0; j < 4; ++j){
      size_t off = (size_t)(m0+ar)*DD + k0 + ac + j*4;
      float4 a = *(const float4*)&p0[off];
      float4 b = *(const float4*)&p1[off];
      a.x += b.x; a.y += b.y; a.z += b.z; a.w += b.w;
      ushort4 u = make_ushort4(f2bf(a.x), f2bf(a.y), f2bf(a.z), f2bf(a.w));
      *(ushort4*)&as[ar][ac + j*4] = u;
    }
    { const bf16x8* src = (const bf16x8*)&Bt[(size_t)(n0+ar)*DD + k0 + ac];
      *(bf16x8*)&bs[ar][ac]   = src[0];
      *(bf16x8*)&bs[ar][ac+8] = src[1];
    }
    __syncthreads();
    const int mr = w*16 + (l & 15);
    const int kb = (l >> 4)*8;
    #pragma unroll
    for (int kc2 = 0; kc2 < 2; ++kc2){
      bf16x8 af = *(const bf16x8*)&as[mr][kc2*32 + kb];
      #pragma unroll
      for (int nt = 0; nt < 4; ++nt){
        bf16x8 bfr = *(const bf16x8*)&bs[nt*16 + (l & 15)][kc2*32 + kb];
        acc[nt] = __builtin_amdgcn_mfma_f32_16x16x32_bf16(af, bfr, acc[nt], 0, 0, 0);
      }
    }
    __syncthreads();
  }
  #pragma unroll
  for (int nt = 0; nt < 4; ++nt){
    int col = n0 + nt*16 + (l & 15);
    #pragma unroll
    for (int r = 0; r < 4; ++r){
      int row = m0 + w*16 + (l >> 4)*4 + r;
      size_t off = (size_t)row*DD + col;
      x[off] = x[off] + y[off] + acc[nt][r];
    }
  }
}

// ------------ causal depthwise conv + silu gating, bf16 in/out ------------
__global__ void k_conv(const unsigned short* __restrict__ u,
                       const unsigned short* __restrict__ g,
                       const float* __restrict__ cw, const float* __restrict__ cb,
                       unsigned short* __restrict__ hh){
  int i8 = blockIdx.x*256 + threadIdx.x;    // over ROWS*DIM/8
  int cg = i8 & 63;
  int bt = i8 >> 6;
  int t  = bt & (TT-1);
  int c0 = cg*8;
  float acc[8];
  { float4 b0 = *(const float4*)&cb[c0];
    float4 b1 = *(const float4*)&cb[c0+4];
    acc[0]=b0.x; acc[1]=b0.y; acc[2]=b0.z; acc[3]=b0.w;
    acc[4]=b1.x; acc[5]=b1.y; acc[6]=b1.z; acc[7]=b1.w; }
  float wts[8][4];
  #pragma unroll
  for (int i = 0; i < 8; ++i) *(float4*)&wts[i][0] = *(const float4*)&cw[(c0+i)*KW];
  #pragma unroll
  for (int j = 0; j < KW; ++j){
    int dt_ = j - (KW-1);
    if (t + dt_ >= 0){
      bf16x8 uv = *(const bf16x8*)&u[(size_t)(bt + dt_)*DIM + c0];
      #pragma unroll
      for (int i = 0; i < 8; ++i)
        acc[i] = fmaf(bf2f((unsigned short)uv[i]), wts[i][j], acc[i]);
    }
  }
  bf16x8 gv = *(const bf16x8*)&g[(size_t)bt*DIM + c0];
  bf16x8 o;
  #pragma unroll
  for (int i = 0; i < 8; ++i){
    float h = siluf(acc[i]);
    o[i] = (short)f2bf(siluf(bf2f((unsigned short)gv[i])) * h);
  }
  *(bf16x8*)&hh[(size_t)bt*DIM + c0] = o;
}

// ---- fused: proj(small GEMM w/ packed weights) + scal + rk-normalize ----
__global__ void __launch_bounds__(256) k_fused(const float* __restrict__ y,
    const float* __restrict__ Wg, const float* __restrict__ Wb,
    const float* __restrict__ Wa, const float* __restrict__ Wbl,
    const float* __restrict__ A_log, const float* __restrict__ dtb,
    float* __restrict__ rkb, float* __restrict__ scal){
  __shared__ float s_y[4][260];
  __shared__ float s_p[4][32];
  const int wv = threadIdx.x >> 6, l = threadIdx.x & 63;
  const int row = blockIdx.x*4 + wv;

  float4 yv = *(const float4*)&y[(size_t)row*DD + l*4];
  *(float4*)&s_y[wv][l*4] = yv;

  float ss = yv.x*yv.x + yv.y*yv.y + yv.z*yv.z + yv.w*yv.w;
  ss = xor1_add(ss); ss = xor2_add(ss);
  ss = ror4_add(ss); ss = ror8_add(ss);
  float inv = 1.f / fmaxf(sqrtf(ss), 1e-12f);
  float4 rv; rv.x = yv.x*inv; rv.y = yv.y*inv; rv.z = yv.z*inv; rv.w = yv.w*inv;
  *(float4*)&rkb[(size_t)row*DD + l*4] = rv;

  __syncthreads();

  const int j = (l < 28) ? l : 27;
  const float* wp; int stride;
  if (j < 4){ wp = Wg + j; stride = HH; }
  else if (j < 12){ int m=(j-4)>>2, h=(j-4)&3; wp = Wb + (size_t)m*DD*HH + h; stride = HH; }
  else if (j < 20){ int m=(j-12)>>2, h=(j-12)&3; wp = Wa + (size_t)m*DD*HH + h; stride = HH; }
  else { wp = Wbl + (j-20); stride = HH*MM; }
  float a0=0.f,a1=0.f,a2=0.f,a3=0.f;
  #pragma unroll 4
  for (int k = 0; k < DD; k += 4){
    a0 = fmaf(s_y[wv][k+0], wp[(k+0)*stride], a0);
    a1 = fmaf(s_y[wv][k+1], wp[(k+1)*stride], a1);
    a2 = fmaf(s_y[wv][k+2], wp[(k+2)*stride], a2);
    a3 = fmaf(s_y[wv][k+3], wp[(k+3)*stride], a3);
  }
  if (l < 28) s_p[wv][l] = (a0+a1)+(a2+a3);

  __syncthreads();

  if (l < 8){
    int m = l >> 2, h = l & 3;
    float gs  = sigf(s_p[wv][h]);
    float btv = sigf(s_p[wv][4 + m*4 + h]);
    float sp  = s_p[wv][12 + m*4 + h] + dtb[m*HH + h];
    sp = (sp > 15.f) ? sp : log1pf(__expf(sp));
    float dc  = __expf(-__expf(A_log[m*HH + h]) * sp);
    float l0 = s_p[wv][20 + h*2], l1 = s_p[wv][20 + h*2 + 1];
    float mx = fmaxf(l0, l1);
    float e0 = __expf(l0-mx), e1 = __expf(l1-mx);
    float bl = (m ? e1 : e0) / (e0 + e1);
    float4 o; o.x = dc; o.y = btv; o.z = bl*gs; o.w = 0.f;
    *(float4*)&scal[((size_t)row*MM + m)*(HH*4) + h*4] = o;
  }
}

// ---------------- sequential delta-memory scan ----------
// (R10 structure: pred(t+1) = read(t) carried in rrc; v staged as bf16)

#define SSTEP(T_, WK, RK, PF, VB, SB) { \
  const float dc = SB.x, btv = SB.y, blg = SB.z; \
  const float v = VB; \
  { const int tn_ = ((T_)+2 < 64) ? (T_)+2 : 63; \
    PF[0] = *(const float4*)&s_rk[p][tn_][dbase + 0]; \
    PF[1] = *(const float4*)&s_rk[p][tn_][dbase + 4]; \
    VB = bf2f(s_v[p][tn_][klocal]); \
    SB = *(const float4*)&s_sc[p][tn_][0]; } \
  const float err = (v - dc*rrc)*btv; \
  float rr0=0.f,rr1=0.f; \
  _Pragma("unroll") \
  for (int jj = 0; jj < 2; ++jj){ const float4 rp = WK[jj]; const float4 rc = RK[jj]; \
    float w0,w1,w2,w3,c0,c1,c2,c3; \
    if (ROT == 0){ w0=rp.x; w1=rp.y; w2=rp.z; w3=rp.w; c0=rc.x; c1=rc.y; c2=rc.z; c3=rc.w; } \
    else { w0=-rp.y; w1=rp.x; w2=-rp.w; w3=rp.z; c0=-rc.y; c1=rc.x; c2=-rc.w; c3=rc.z; } \
    S[4*jj+0] = fmaf(S[4*jj+0], dc, w0*err); rr0 = fmaf(S[4*jj+0], c0, rr0); \
    S[4*jj+1] = fmaf(S[4*jj+1], dc, w1*err); rr1 = fmaf(S[4*jj+1], c1, rr1); \
    S[4*jj+2] = fmaf(S[4*jj+2], dc, w2*err); rr0 = fmaf(S[4*jj+2], c2, rr0); \
    S[4*jj+3] = fmaf(S[4*jj+3], dc, w3*err); rr1 = fmaf(S[4*jj+3], c3, rr1); } \
  float rr = rr0 + rr1; \
  rr = xor1_add(rr); rr = xor2_add(rr); rr = xor8_add(rr); \
  rrc = rr; \
  if (q == 0) part[(size_t)(rowchunk + (T_))*DD + h*HDIM + kq*8 + klocal] = blg*rr; \
}

template<int ROT>
__device__ __forceinline__ void scan_body(int b, int h, int kq, int l,
    const unsigned short* __restrict__ vals, const float* __restrict__ rkb,
    const float* __restrict__ scal, float* __restrict__ part,
    float (*s_rk)[64][64], unsigned short (*s_v)[64][8], float (*s_sc)[64][4])
{
  const int q = (l & 3) | ((l & 8) >> 1);             // bits 0,1,3
  const int klocal = ((l >> 2) & 1) | ((l >> 3) & 6); // bits 2,4,5
  const int dbase = q*8;
  const int rowbase = b*TT;

  float S[8];
  #pragma unroll
  for (int j = 0; j < 8; ++j) S[j] = 0.f;
  const float4 Z = make_float4(0.f,0.f,0.f,0.f);
  float4 rb0[2]={Z,Z}, rb1[2]={Z,Z}, rb2[2]={Z,Z}, rb3[2]={Z,Z};
  float vb0 = 0.f, vb1 = 0.f;
  float4 sb0 = Z, sb1 = Z;
  float rrc = 0.f;    // carried read-dot == next step's pred

  auto stage = [&](int c, int pbuf){
    const int r0 = rowbase + c*64;
    #pragma unroll
    for (int i = 0; i < 16; ++i){
      const float* g = rkb + (size_t)(r0 + i*4 + (l>>4))*DD + h*HDIM + (l&15)*4;
      gl_lds16(g, &s_rk[pbuf][i*4][0]);
    }
    { const unsigned short* g = vals + ((size_t)(r0 + l)*MM + ROT)*DD + h*HDIM + kq*8;
      gl_lds16(g, &s_v[pbuf][0][0]); }
    { const float* g = scal + ((size_t)(r0 + l)*MM + ROT)*(HH*4) + h*4;
      gl_lds16(g, &s_sc[pbuf][0][0]); }
  };

  stage(0, 0);
  for (int c = 0; c < TT/64; ++c){
    const int p = c & 1;
    __syncthreads();                 // vmcnt drain: chunk c staged
    if (c + 1 < TT/64) stage(c+1, p^1);
    rb0[0] = *(const float4*)&s_rk[p][0][dbase]; rb0[1] = *(const float4*)&s_rk[p][0][dbase+4];
    rb1[0] = *(const float4*)&s_rk[p][1][dbase]; rb1[1] = *(const float4*)&s_rk[p][1][dbase+4];
    vb0 = bf2f(s_v[p][0][klocal]); vb1 = bf2f(s_v[p][1][klocal]);
    sb0 = *(const float4*)&s_sc[p][0][0]; sb1 = *(const float4*)&s_sc[p][1][0];
    const int rowchunk = rowbase + c*64;
    for (int tt = 0; tt < 64; tt += 4){
      SSTEP(tt+0, rb3, rb0, rb2, vb0, sb0)
      SSTEP(tt+1, rb0, rb1, rb3, vb1, sb1)
      SSTEP(tt+2, rb1, rb2, rb0, vb0, sb0)
      SSTEP(tt+3, rb2, rb3, rb1, vb1, sb1)
    }
  }
}

__global__ void __launch_bounds__(64) k_scan(const unsigned short* __restrict__ vals,
                                             const float* __restrict__ rkb,
                                             const float* __restrict__ scal,
                                             float* __restrict__ partials){
  __shared__ float s_rk[2][64][64];
  __shared__ unsigned short s_v[2][64][8];
  __shared__ float s_sc[2][64][4];
  const int bi = blockIdx.x;      // (((b*HH)+h)*MM + m)*8 + kq
  const int kq = bi & 7;
  const int m  = (bi >> 3) & 1;
  const int h  = (bi >> 4) & 3;
  const int b  = bi >> 6;
  float* part = partials + (size_t)m*(BB*TT*DD);
  if (m == 0) scan_body<0>(b, h, kq, threadIdx.x, vals, rkb, scal, part, s_rk, s_v, s_sc);
  else        scan_body<1>(b, h, kq, threadIdx.x, vals, rkb, scal, part, s_rk, s_v, s_sc);
}

extern "C" void kernel_launch(void* const* d_in, const int* in_sizes, int n_in,
                              void* d_out, int out_size, void* d_ws, size_t ws_size,
                              hipStream_t stream){
  const int*   ids   = (const int*)d_in[0];
  const float* emb   = (const float*)d_in[1];
  const float* normw = (const float*)d_in[2];
  const float* Wup   = (const float*)d_in[3];
  const float* Wgate = (const float*)d_in[4];
  const float* Wdown = (const float*)d_in[5];
  const float* convw = (const float*)d_in[6];
  const float* convb = (const float*)d_in[7];
  const float* Wv    = (const float*)d_in[8];
  const float* Wg    = (const float*)d_in[9];
  const float* Wb    = (const float*)d_in[10];
  const float* Wa    = (const float*)d_in[11];
  const float* A_log = (const float*)d_in[12];
  const float* dtb   = (const float*)d_in[13];
  const float* Wbl   = (const float*)d_in[14];
  const float* Wout  = (const float*)d_in[15];
  const float* fnw   = (const float*)d_in[16];
  float* out = (float*)d_out;

  const int ROWS = BB*TT;              // 4096
  const size_t MEG = 1u << 20;
  float* ws   = (float*)d_ws;
  float* x    = ws;                        // 1M f32 (residual)
  unsigned short* nyb = (unsigned short*)(x + MEG);    // 0.5M floats = 1M bf16 (nx / yb)
  float* big1 = x + MEG + MEG/2;           // 2M floats: ub (1M-eq) | gb/hhb (1M-eq); later valsb in ub
  float* big2 = big1 + 2*MEG;              // 2M f32: partials
  float* y    = big2 + 2*MEG;              // 1M f32
  float* rkb  = y    + MEG;                // 1M f32
  float* scal = rkb  + MEG;                // 128K f32
  unsigned short* wbf = (unsigned short*)(scal + (1u<<17));  // 1.25M ushorts

  unsigned short* ub  = (unsigned short*)big1;         // 4096x512 bf16
  unsigned short* gb  = (unsigned short*)(big1 + MEG); // 4096x512 bf16 (becomes hhb)
  unsigned short* valsb = ub;                          // reuse after conv

  // one-time: convert+transpose all weights (both layers) + emb to bf16
  { int total = 2*LWB + VV*DD;
    k_cvt<<<(total + 255)/256, 256, 0, stream>>>(Wup, Wgate, Wdown, Wv, Wout, emb, wbf); }

  k_embed<<<ROWS, DD, 0, stream>>>(ids, emb, x);

  for (int l = 0; l < LL; ++l){
    unsigned short* wl = wbf + (size_t)l*LWB;
    unsigned short* upT   = wl;
    unsigned short* gateT = wl + 131072;
    unsigned short* downT = wl + 262144;
    unsigned short* wvT   = wl + 393216;
    unsigned short* woutT = wl + 524288;

    k_rmsnorm<<<ROWS, 64, 0, stream>>>(x, normw + l*DD, nyb);
    k_gemm_up<<<dim3(DIM/64, ROWS/64), 256, 0, stream>>>(nyb, upT, gateT, ub, gb);
    k_conv<<<(ROWS*DIM/8)/256, 256, 0, stream>>>(ub, gb, convw + l*DIM*KW, convb + l*DIM, gb);
    // down: y (f32) + yb (bf16, into nyb)
    k_gemm2<2><<<dim3(DD/64, ROWS/64), 256, 0, stream>>>(gb, downT, y, nyb, DD, DIM);
    // vals bf16
    k_gemm2<1><<<dim3(DIM/64, ROWS/64), 256, 0, stream>>>(nyb, wvT, nullptr, valsb, DIM, DD);
    k_fused<<<ROWS/4, 256, 0, stream>>>(y, Wg + l*DD*HH, Wb + (size_t)l*MM*DD*HH,
                                        Wa + (size_t)l*MM*DD*HH, Wbl + l*DD*HH*MM,
                                        A_log + l*MM*HH, dtb + l*MM*HH, rkb, scal);
    k_scan<<<BB*HH*MM*8, 64, 0, stream>>>(valsb, rkb, scal, big2);
    k_gemm_wout<<<dim3(DD/64, ROWS/64), 256, 0, stream>>>(big2, big2 + MEG, woutT, y, x);
  }

  unsigned short* embT = wbf + 2*LWB;   // [272][256] bf16
  k_rmsnorm<<<ROWS, 64, 0, stream>>>(x, fnw, nyb);
  k_gemm2<0><<<dim3((VV+63)/64, ROWS/64), 256, 0, stream>>>(nyb, embT, out, nullptr, VV, DD);
}